// Round 7
// baseline (1313.487 us; speedup 1.0000x reference)
//
#include <hip/hip_runtime.h>
#include <hip/hip_bf16.h>
#include <math.h>

// Problem: S=512, B=128, V=50257, D=300, H=512
#define S_LEN 512
#define B_N   128
#define D_EMB 300
#define KP    320   // D padded to multiple of 32 (zero-filled)
#define H_N   512

typedef __attribute__((ext_vector_type(8)))  short short8;       // 8 bf16 (4 VGPRs)
typedef __attribute__((ext_vector_type(8)))  unsigned short ushort8;
typedef __attribute__((ext_vector_type(4)))  unsigned int uint4v;
typedef __attribute__((ext_vector_type(4)))  float float4v;
typedef __attribute__((ext_vector_type(16))) float float16v;

__device__ __forceinline__ unsigned short f32_to_bf16(float f) {
  unsigned u = __float_as_uint(f);
  u = (u + 0x7fffu + ((u >> 16) & 1u)) >> 16;   // RNE
  return (unsigned short)u;
}
__device__ __forceinline__ float bf16_to_f32(unsigned short h) {
  return __uint_as_float(((unsigned)h) << 16);
}
__device__ __forceinline__ short8 as_short8(uint4v v) {
  union { uint4v u; short8 s; } c; c.u = v; return c.s;
}

// ---------------------------------------------------------------------------
// K1: embeds = embed_mat[ends]; xn = embeds / max(||embeds||,eps)
// writes xn as split bf16 (hi+lo), layout [b][s][KP], k 300..319 zero.
// ---------------------------------------------------------------------------
__global__ __launch_bounds__(256) void k1_embed_norm(
    const int* __restrict__ ends, const float* __restrict__ emb,
    unsigned short* __restrict__ xh, unsigned short* __restrict__ xl) {
  int wave = threadIdx.x >> 6, lane = threadIdx.x & 63;
  int vec = blockIdx.x * 4 + wave;            // vec = s*B + b (ends is [S][B])
  int b = vec & (B_N - 1), s = vec >> 7;
  int v = ends[vec];
  const float* row = emb + (size_t)v * D_EMB;
  float e0 = row[lane], e1 = row[lane + 64], e2 = row[lane + 128], e3 = row[lane + 192];
  float e4 = (lane + 256 < D_EMB) ? row[lane + 256] : 0.f;
  float ss = e0*e0 + e1*e1 + e2*e2 + e3*e3 + e4*e4;
  #pragma unroll
  for (int m = 1; m < 64; m <<= 1) ss += __shfl_xor(ss, m);
  float sc = 1.0f / fmaxf(sqrtf(ss), 1e-8f);
  size_t base = ((size_t)b * S_LEN + s) * KP;
  float xs[5] = { e0*sc, e1*sc, e2*sc, e3*sc, (lane + 256 < D_EMB) ? e4*sc : 0.f };
  #pragma unroll
  for (int i = 0; i < 5; ++i) {
    unsigned short hi = f32_to_bf16(xs[i]);
    unsigned short lo = f32_to_bf16(xs[i] - bf16_to_f32(hi));
    xh[base + lane + 64*i] = hi;
    xl[base + lane + 64*i] = lo;
  }
}

// ---------------------------------------------------------------------------
// K2: feats[i][b] = max_{j<i} dot(xn[i,b], xn[j,b]); feats[0]=0
// Split-bf16 MFMA 32x32x16 (hi*hi + hi*lo + lo*hi).
// R11: A-operand fragments loaded straight from global into registers
// (identical element mapping as the old LDS path; L2-hot after jc=0),
// LDS stages only B (22.5KB -> ~2x co-residency), grid is (b, ic) so all
// ic-chunks of a batch share one XCD L2 (same %8 mapping k3 relies on).
// ---------------------------------------------------------------------------
#define KC  80
#define LDP 88      // LDS row stride in ushorts (conflict-friendly, 16B aligned)

__global__ __launch_bounds__(256) void k2_feats(
    const unsigned short* __restrict__ xh, const unsigned short* __restrict__ xl,
    float* __restrict__ feats) {
  __shared__ __align__(16) unsigned short sBh[64*LDP], sBl[64*LDP];
  __shared__ float rbuf[4][32];
  int b   = blockIdx.x;          // 0..127 (b&7 selects XCD)
  int ic  = blockIdx.y;          // 0..7
  int tid = threadIdx.x;
  int wave = tid >> 6, lane = tid & 63;
  int itl = wave & 1, jtl = wave >> 1;
  int itg = ic * 2 + itl;        // global 32-row i-tile index
  size_t xbase = (size_t)b * S_LEN * KP;
  int arow0 = ic * 64;
  // my A row (m = lane&31) and k-quad offset
  const size_t arowoff = xbase + (size_t)(arow0 + itl * 32 + (lane & 31)) * KP
                       + (size_t)((lane >> 5) * 8);

  float rm[16];
  #pragma unroll
  for (int r = 0; r < 16; ++r) rm[r] = -INFINITY;

  for (int jc = 0; jc <= ic; ++jc) {
    int jt = jc * 2 + jtl;
    bool active = (jt <= itg);
    float16v acc;
    #pragma unroll
    for (int r = 0; r < 16; ++r) acc[r] = 0.f;

    for (int kc = 0; kc < 4; ++kc) {
      // A fragments: direct global->register (10 x 16B per lane)
      short8 a_h[5], a_l[5];
      #pragma unroll
      for (int ks = 0; ks < 5; ++ks) {
        size_t ga = arowoff + kc * KC + ks * 16;
        a_h[ks] = *(const short8*)&xh[ga];
        a_l[ks] = *(const short8*)&xl[ga];
      }
      __syncthreads();
      for (int u = tid; u < 640; u += 256) {     // 64 rows x 10 16B-segs (B only)
        int r = u / 10, sg = u % 10;
        size_t gb = xbase + (size_t)(jc*64 + r) * KP + kc*KC + sg*8;
        int la = r * LDP + sg * 8;
        *(ushort8*)&sBh[la] = *(const ushort8*)&xh[gb];
        *(ushort8*)&sBl[la] = *(const ushort8*)&xl[gb];
      }
      __syncthreads();
      if (active) {
        int br = (jtl*32 + (lane & 31)) * LDP;
        int kq = (lane >> 5) * 8;
        #pragma unroll
        for (int ks = 0; ks < 5; ++ks) {
          short8 b_h = *(const short8*)&sBh[br + ks*16 + kq];
          short8 b_l = *(const short8*)&sBl[br + ks*16 + kq];
          acc = __builtin_amdgcn_mfma_f32_32x32x16_bf16(a_h[ks], b_h, acc, 0, 0, 0);
          acc = __builtin_amdgcn_mfma_f32_32x32x16_bf16(a_h[ks], b_l, acc, 0, 0, 0);
          acc = __builtin_amdgcn_mfma_f32_32x32x16_bf16(a_l[ks], b_h, acc, 0, 0, 0);
        }
      }
    }
    if (active) {
      int colg = jt * 32 + (lane & 31);
      #pragma unroll
      for (int r = 0; r < 16; ++r) {
        int rowg = itg * 32 + (r & 3) + 8*(r >> 2) + 4*(lane >> 5);
        float v = acc[r];
        if (jt == itg && colg >= rowg) v = -INFINITY;  // causal: j<i
        rm[r] = fmaxf(rm[r], v);
      }
    }
  }
  #pragma unroll
  for (int r = 0; r < 16; ++r) {
    float v = rm[r];
    v = fmaxf(v, __shfl_xor(v, 1));
    v = fmaxf(v, __shfl_xor(v, 2));
    v = fmaxf(v, __shfl_xor(v, 4));
    v = fmaxf(v, __shfl_xor(v, 8));
    v = fmaxf(v, __shfl_xor(v, 16));
    rm[r] = v;
  }
  if ((lane & 31) == 0) {
    int half = lane >> 5;
    #pragma unroll
    for (int r = 0; r < 16; ++r)
      rbuf[wave][(r & 3) + 8*(r >> 2) + 4*half] = rm[r];
  }
  __syncthreads();
  if (tid < 64) {   // merge jt-parities, write feats
    int it2 = tid >> 5, rl = tid & 31;
    float v = fmaxf(rbuf[it2][rl], rbuf[it2 + 2][rl]);
    int i = ic * 64 + it2 * 32 + rl;
    feats[i * B_N + b] = (i == 0) ? 0.0f : v;
  }
}

// ---------------------------------------------------------------------------
// K3: GRU, persistent cooperative kernel. R18: 128 WGs x 512 thr
// (16 WGs/group x 32 j each; was 32 x 16).
// FROZEN R8 signal skeleton: wg-scope producer stores -> vmcnt(0) ->
// __syncthreads -> tid0 WG-flag store; consumer flag poll with s_sleep.
// LEDGER: per-wave PRODUCER flag fanouts fast-fail 3/3 (R5/R6/R9);
// counter-RMW flags regress (R10); poison-spin data-as-signal +16% (R12);
// R13 coalesced consumer load -360us; R14 fragment-major layout -253us;
// R15 conflict-free reduce -19us (conflicts were overlapped); R16 chain
// split +24us, R17 2 waves/SIMD -46us and MFMA busy-cy/step NEVER moved
// across R15/R16/R17 -> MFMA is NOT the critical path; chain = protocol
// hops + producer-skew tail + L2 transaction bursts.
// R18: producer:fragment 1:1 (s owns fragment g*16+s, j in [32s,32s+32));
// each consumer wave polls exactly 2 flags; skew tail = max over 16 (not
// 32); per-XCD fan-out 1MB -> 512KB/step; polls 4x fewer; flags halved.
// Per-wave MFMA doubles to 36 (2 n-tiles) - safe, MFMA proven non-critical.
// Same per-acc MFMA order + same 8-partial reduce order -> bit-identical.
// ---------------------------------------------------------------------------
#define HW64 (B_N * H_N / 2)   // 8B words per parity buffer (= 32768)

__global__ __launch_bounds__(512, 1) void k3_gru(
    const float* __restrict__ feats,
    const float* __restrict__ w_ih, const float* __restrict__ w_hh,
    const float* __restrict__ b_ih, const float* __restrict__ b_hh,
    const float* __restrict__ fc_w, const float* __restrict__ fc_b,
    unsigned long long* __restrict__ hq, unsigned int* __restrict__ bars,
    float* __restrict__ out) {
  // [(wave<<1)|nt][batch][col] = {r,z,n,pad} : 64KB
  __shared__ __align__(16) float4v red2[16][16][16];
  __shared__ float osum[512];
  int tid = threadIdx.x;
  int wave = tid >> 6, lane = tid & 63;
  int g = blockIdx.x & 7, s = blockIdx.x >> 3;   // s in [0,16)

  // --- stationary W_hh fragments (B-operand: n=lane&15, k=quad*8+j)
  // wave w covers K slice [64w, 64w+64): local ks in {0,1}; 2 n-tiles.
  short8 wfh[3][2][2], wfl[3][2][2];   // [gate][ks][nt]
  {
    int nloc = lane & 15;
    int kq = (lane >> 4) * 8;
    #pragma unroll
    for (int gt = 0; gt < 3; ++gt) {
      #pragma unroll
      for (int nt = 0; nt < 2; ++nt) {
        const float* wr = w_hh + (size_t)(gt * H_N + s * 32 + nt * 16 + nloc) * H_N;
        #pragma unroll
        for (int ks = 0; ks < 2; ++ks) {
          int k0 = wave * 64 + ks * 32 + kq;
          short8 h8, l8;
          #pragma unroll
          for (int j = 0; j < 8; ++j) {
            float wv = wr[k0 + j];
            unsigned short hi = f32_to_bf16(wv);
            unsigned short lo = f32_to_bf16(wv - bf16_to_f32(hi));
            h8[j] = (short)hi; l8[j] = (short)lo;
          }
          wfh[gt][ks][nt] = h8; wfl[gt][ks][nt] = l8;
        }
      }
    }
  }
  // --- per-thread gate constants: thread = (bb, jj), all 512 gate
  int bb = tid >> 5, jj = tid & 31;
  int jr = s * 32 + jj;
  float wihr = w_ih[jr], wihz = w_ih[H_N + jr], wihn = w_ih[2*H_N + jr];
  float bir = b_ih[jr],  biz = b_ih[H_N + jr],  bin_ = b_ih[2*H_N + jr];
  float bhr = b_hh[jr],  bhz = b_hh[H_N + jr],  bhn = b_hh[2*H_N + jr];
  float fcw = fc_w[jr];
  int gb = g * 16 + bb;
  float h_old = 0.f;
  // wave w polls its 2 fragment producers s in {2w, 2w+1}
  const unsigned int* fp = bars + g * 16 + wave * 2 + (lane & 1);
  unsigned int* myflag = bars + g * 16 + s;

  // producer: fragment C = g*16+s; k_local=jj, q=jj>>3, e=jj&7, m=bb
  const size_t prodoff = (size_t)(g * 16 + s) * 512
                       + (size_t)(jj >> 3) * 128 + (size_t)bb * 8;
  // consumer: wave w owns fragments g*16 + 2w, +1
  const size_t cbase = (size_t)(g * 16 + wave * 2) * 512 + (size_t)lane * 8;

  for (int t = 0; t < S_LEN; ++t) {
    // feats load hoisted above the poll — independent, overlaps the spin
    float x = feats[t * B_N + gb];
    float sr = 0.f, sz = 0.f, sn = 0.f;
    if (t > 0) {
      // ---- wait: this wave's 2 producers stored h_{t-1} (flag >= t)
      {
        const unsigned tgt = (unsigned)t;
        for (;;) {
          unsigned f = __hip_atomic_load(fp, __ATOMIC_RELAXED, __HIP_MEMORY_SCOPE_AGENT);
          if (__ballot(f < tgt) == 0ull) break;
          __builtin_amdgcn_s_sleep(1);
        }
        asm volatile("" ::: "memory");
      }
      const unsigned short* hh =
          (const unsigned short*)(hq + (size_t)((t - 1) & 1) * HW64);
      const unsigned short* hbase = hh + cbase;        // hi fragments
      const unsigned short* lbase = hbase + 65536;     // lo fragments
      // 4x dwordx4 sc1 (L1-bypass), each 64-lane instr = 1KB contiguous.
      uint4v rh0, rh1, rl0, rl1;
      asm volatile(
        "global_load_dwordx4 %0, %4, off sc1\n\t"
        "global_load_dwordx4 %1, %4, off offset:1024 sc1\n\t"
        "global_load_dwordx4 %2, %5, off sc1\n\t"
        "global_load_dwordx4 %3, %5, off offset:1024 sc1\n\t"
        "s_waitcnt vmcnt(0)"
        : "=&v"(rh0), "=&v"(rh1), "=&v"(rl0), "=&v"(rl1)
        : "v"(hbase), "v"(lbase)
        : "memory");
      short8 ah0 = as_short8(rh0), ah1 = as_short8(rh1);
      short8 al0 = as_short8(rl0), al1 = as_short8(rl1);
      // 36 MFMAs: 2 ks x {hh,hl,lh} x 2 nt x 3 gates.
      // Per-acc order: ks0{hh,hl,lh}, ks1{hh,hl,lh} (= R17, bit-identical).
      float4v a00, a01, a02, a10, a11, a12;   // [nt][gate]
      #pragma unroll
      for (int r = 0; r < 4; ++r) {
        a00[r]=0.f; a01[r]=0.f; a02[r]=0.f; a10[r]=0.f; a11[r]=0.f; a12[r]=0.f;
      }
      // ks0 hh
      a00 = __builtin_amdgcn_mfma_f32_16x16x32_bf16(ah0, wfh[0][0][0], a00, 0,0,0);
      a01 = __builtin_amdgcn_mfma_f32_16x16x32_bf16(ah0, wfh[1][0][0], a01, 0,0,0);
      a02 = __builtin_amdgcn_mfma_f32_16x16x32_bf16(ah0, wfh[2][0][0], a02, 0,0,0);
      a10 = __builtin_amdgcn_mfma_f32_16x16x32_bf16(ah0, wfh[0][0][1], a10, 0,0,0);
      a11 = __builtin_amdgcn_mfma_f32_16x16x32_bf16(ah0, wfh[1][0][1], a11, 0,0,0);
      a12 = __builtin_amdgcn_mfma_f32_16x16x32_bf16(ah0, wfh[2][0][1], a12, 0,0,0);
      // ks0 hl
      a00 = __builtin_amdgcn_mfma_f32_16x16x32_bf16(ah0, wfl[0][0][0], a00, 0,0,0);
      a01 = __builtin_amdgcn_mfma_f32_16x16x32_bf16(ah0, wfl[1][0][0], a01, 0,0,0);
      a02 = __builtin_amdgcn_mfma_f32_16x16x32_bf16(ah0, wfl[2][0][0], a02, 0,0,0);
      a10 = __builtin_amdgcn_mfma_f32_16x16x32_bf16(ah0, wfl[0][0][1], a10, 0,0,0);
      a11 = __builtin_amdgcn_mfma_f32_16x16x32_bf16(ah0, wfl[1][0][1], a11, 0,0,0);
      a12 = __builtin_amdgcn_mfma_f32_16x16x32_bf16(ah0, wfl[2][0][1], a12, 0,0,0);
      // ks0 lh
      a00 = __builtin_amdgcn_mfma_f32_16x16x32_bf16(al0, wfh[0][0][0], a00, 0,0,0);
      a01 = __builtin_amdgcn_mfma_f32_16x16x32_bf16(al0, wfh[1][0][0], a01, 0,0,0);
      a02 = __builtin_amdgcn_mfma_f32_16x16x32_bf16(al0, wfh[2][0][0], a02, 0,0,0);
      a10 = __builtin_amdgcn_mfma_f32_16x16x32_bf16(al0, wfh[0][0][1], a10, 0,0,0);
      a11 = __builtin_amdgcn_mfma_f32_16x16x32_bf16(al0, wfh[1][0][1], a11, 0,0,0);
      a12 = __builtin_amdgcn_mfma_f32_16x16x32_bf16(al0, wfh[2][0][1], a12, 0,0,0);
      // ks1 hh
      a00 = __builtin_amdgcn_mfma_f32_16x16x32_bf16(ah1, wfh[0][1][0], a00, 0,0,0);
      a01 = __builtin_amdgcn_mfma_f32_16x16x32_bf16(ah1, wfh[1][1][0], a01, 0,0,0);
      a02 = __builtin_amdgcn_mfma_f32_16x16x32_bf16(ah1, wfh[2][1][0], a02, 0,0,0);
      a10 = __builtin_amdgcn_mfma_f32_16x16x32_bf16(ah1, wfh[0][1][1], a10, 0,0,0);
      a11 = __builtin_amdgcn_mfma_f32_16x16x32_bf16(ah1, wfh[1][1][1], a11, 0,0,0);
      a12 = __builtin_amdgcn_mfma_f32_16x16x32_bf16(ah1, wfh[2][1][1], a12, 0,0,0);
      // ks1 hl
      a00 = __builtin_amdgcn_mfma_f32_16x16x32_bf16(ah1, wfl[0][1][0], a00, 0,0,0);
      a01 = __builtin_amdgcn_mfma_f32_16x16x32_bf16(ah1, wfl[1][1][0], a01, 0,0,0);
      a02 = __builtin_amdgcn_mfma_f32_16x16x32_bf16(ah1, wfl[2][1][0], a02, 0,0,0);
      a10 = __builtin_amdgcn_mfma_f32_16x16x32_bf16(ah1, wfl[0][1][1], a10, 0,0,0);
      a11 = __builtin_amdgcn_mfma_f32_16x16x32_bf16(ah1, wfl[1][1][1], a11, 0,0,0);
      a12 = __builtin_amdgcn_mfma_f32_16x16x32_bf16(ah1, wfl[2][1][1], a12, 0,0,0);
      // ks1 lh
      a00 = __builtin_amdgcn_mfma_f32_16x16x32_bf16(al1, wfh[0][1][0], a00, 0,0,0);
      a01 = __builtin_amdgcn_mfma_f32_16x16x32_bf16(al1, wfh[1][1][0], a01, 0,0,0);
      a02 = __builtin_amdgcn_mfma_f32_16x16x32_bf16(al1, wfh[2][1][0], a02, 0,0,0);
      a10 = __builtin_amdgcn_mfma_f32_16x16x32_bf16(al1, wfh[0][1][1], a10, 0,0,0);
      a11 = __builtin_amdgcn_mfma_f32_16x16x32_bf16(al1, wfh[1][1][1], a11, 0,0,0);
      a12 = __builtin_amdgcn_mfma_f32_16x16x32_bf16(al1, wfh[2][1][1], a12, 0,0,0);
      // C/D: row(batch)=(lane>>4)*4+reg, col(j)=lane&15. float4 {r,z,n,pad}.
      int colw = lane & 15, roww = (lane >> 4) * 4;
      #pragma unroll
      for (int r = 0; r < 4; ++r) {
        float4v w0; w0[0] = a00[r]; w0[1] = a01[r]; w0[2] = a02[r]; w0[3] = 0.f;
        float4v w1; w1[0] = a10[r]; w1[1] = a11[r]; w1[2] = a12[r]; w1[3] = 0.f;
        red2[wave * 2 + 0][roww + r][colw] = w0;
        red2[wave * 2 + 1][roww + r][colw] = w1;
      }
      __syncthreads();
      int ntc = jj >> 4, colc = jj & 15;
      float4v sv = red2[ntc][bb][colc];
      #pragma unroll
      for (int w8 = 1; w8 < 8; ++w8) sv += red2[w8 * 2 + ntc][bb][colc];
      sr = sv[0]; sz = sv[1]; sn = sv[2];
    }
    // gates: exact identities on fast exp; clamp to dodge inf/inf
    float ar_ = fminf(fmaxf(x * wihr + bir + sr + bhr, -30.f), 30.f);
    float az_ = fminf(fmaxf(x * wihz + biz + sz + bhz, -30.f), 30.f);
    float r_ = __builtin_amdgcn_rcpf(1.f + __expf(-ar_));
    float z_ = __builtin_amdgcn_rcpf(1.f + __expf(-az_));
    float an_ = fminf(fmaxf(x * wihn + bin_ + r_ * (sn + bhn), -30.f), 30.f);
    float en = __expf(-2.f * an_);
    float n_ = (1.f - en) * __builtin_amdgcn_rcpf(1.f + en);
    float h_new = (1.f - z_) * n_ + z_ * h_old;
    h_old = h_new;
    if (t < S_LEN - 1) {
      unsigned short hi16 = f32_to_bf16(h_new);
      unsigned short lo16 = f32_to_bf16(h_new - bf16_to_f32(hi16));
      // 3-round shfl_xor allgather over jj&7 -> full 8-elem run in 4 dwords.
      unsigned myh = hi16, myl = lo16;
      unsigned oh = (unsigned)__shfl_xor((int)myh, 1);
      unsigned ol = (unsigned)__shfl_xor((int)myl, 1);
      bool od1 = (jj & 1) != 0;
      unsigned pH = od1 ? (oh | (myh << 16)) : (myh | (oh << 16));  // [e even|e odd]
      unsigned pL = od1 ? (ol | (myl << 16)) : (myl | (ol << 16));
      unsigned qh = (unsigned)__shfl_xor((int)pH, 2);
      unsigned ql = (unsigned)__shfl_xor((int)pL, 2);
      bool od2 = (jj & 2) != 0;
      unsigned h01 = od2 ? qh : pH, h23 = od2 ? pH : qh;   // pairs e01,e23
      unsigned l01 = od2 ? ql : pL, l23 = od2 ? pL : ql;
      unsigned xh01 = (unsigned)__shfl_xor((int)h01, 4);
      unsigned xh23 = (unsigned)__shfl_xor((int)h23, 4);
      unsigned xl01 = (unsigned)__shfl_xor((int)l01, 4);
      unsigned xl23 = (unsigned)__shfl_xor((int)l23, 4);
      bool od4 = (jj & 4) != 0;
      uint4v runH, runL;
      runH[0] = od4 ? xh01 : h01; runH[1] = od4 ? xh23 : h23;
      runH[2] = od4 ? h01 : xh01; runH[3] = od4 ? h23 : xh23;
      runL[0] = od4 ? xl01 : l01; runL[1] = od4 ? xl23 : l23;
      runL[2] = od4 ? l01 : xl01; runL[3] = od4 ? l23 : xl23;
      unsigned short* hh = (unsigned short*)(hq + (size_t)(t & 1) * HW64);
      if ((jj & 3) == 0) {   // jj&7==0: hi run; jj&7==4: lo run
        if ((jj & 4) == 0) *(uint4v*)(hh + prodoff)         = runH;
        else               *(uint4v*)(hh + 65536 + prodoff) = runL;
      }
      // drain own stores (ack at L2), WG barrier, then flag (wg-scope)
      asm volatile("s_waitcnt vmcnt(0)" ::: "memory");
      __syncthreads();
      if (tid == 0)
        __hip_atomic_store(myflag, (unsigned)(t + 1),
                           __ATOMIC_RELAXED, __HIP_MEMORY_SCOPE_WORKGROUP);
    }
  }
  // --- epilogue: out[b] = h_last . fc_w + fc_b
  osum[tid] = h_old * fcw;
  __syncthreads();
  if (jj == 0) {
    float acc = 0.f;
    #pragma unroll
    for (int q = 0; q < 32; ++q) acc += osum[bb * 32 + q];
    if (s == 0) acc += fc_b[0];
    atomicAdd(&out[gb], acc);
  }
}

// ---------------------------------------------------------------------------
extern "C" void kernel_launch(void* const* d_in, const int* in_sizes, int n_in,
                              void* d_out, int out_size, void* d_ws, size_t ws_size,
                              hipStream_t stream) {
  (void)in_sizes; (void)n_in; (void)out_size; (void)ws_size;
  const int*   ends = (const int*)d_in[1];
  const float* emb  = (const float*)d_in[3];
  const float* w_ih = (const float*)d_in[4];
  const float* w_hh = (const float*)d_in[5];
  const float* b_ih = (const float*)d_in[6];
  const float* b_hh = (const float*)d_in[7];
  const float* fc_w = (const float*)d_in[8];
  const float* fc_b = (const float*)d_in[9];
  float* out = (float*)d_out;

  size_t xn_elems = (size_t)B_N * S_LEN * KP;
  unsigned short* xh = (unsigned short*)d_ws;
  unsigned short* xl = xh + xn_elems;
  float* feats = (float*)(xl + xn_elems);
  unsigned long long* hq = (unsigned long long*)(feats + S_LEN * B_N);
  unsigned int* bars = (unsigned int*)(hq + 2 * (size_t)HW64);

  hipMemsetAsync(out, 0, sizeof(float) * B_N, stream);
  hipMemsetAsync(bars, 0, 4096, stream);   // 8 groups x 16 WG flags (zeroed wide)

  k1_embed_norm<<<dim3(S_LEN * B_N / 4), dim3(256), 0, stream>>>(ends, emb, xh, xl);
  k2_feats<<<dim3(B_N, 8), dim3(256), 0, stream>>>(xh, xl, feats);

  void* args[] = { (void*)&feats, (void*)&w_ih, (void*)&w_hh, (void*)&b_ih,
                   (void*)&b_hh, (void*)&fc_w, (void*)&fc_b,
                   (void*)&hq, (void*)&bars, (void*)&out };
  hipLaunchCooperativeKernel((void*)k3_gru, dim3(128), dim3(512), args, 0, stream);
}

// Round 8
// 1069.832 us; speedup vs baseline: 1.2278x; 1.2278x over previous
//
#include <hip/hip_runtime.h>
#include <hip/hip_bf16.h>
#include <math.h>

// Problem: S=512, B=128, V=50257, D=300, H=512
#define S_LEN 512
#define B_N   128
#define D_EMB 300
#define KP    320   // D padded to multiple of 32 (zero-filled)
#define H_N   512

typedef __attribute__((ext_vector_type(8)))  short short8;       // 8 bf16 (4 VGPRs)
typedef __attribute__((ext_vector_type(8)))  unsigned short ushort8;
typedef __attribute__((ext_vector_type(4)))  unsigned int uint4v;
typedef __attribute__((ext_vector_type(4)))  float float4v;
typedef __attribute__((ext_vector_type(16))) float float16v;

__device__ __forceinline__ unsigned short f32_to_bf16(float f) {
  unsigned u = __float_as_uint(f);
  u = (u + 0x7fffu + ((u >> 16) & 1u)) >> 16;   // RNE
  return (unsigned short)u;
}
__device__ __forceinline__ float bf16_to_f32(unsigned short h) {
  return __uint_as_float(((unsigned)h) << 16);
}
__device__ __forceinline__ short8 as_short8(uint4v v) {
  union { uint4v u; short8 s; } c; c.u = v; return c.s;
}

// ---------------------------------------------------------------------------
// K1: embeds = embed_mat[ends]; xn = embeds / max(||embeds||,eps)
// writes xn as split bf16 (hi+lo), layout [b][s][KP], k 300..319 zero.
// ---------------------------------------------------------------------------
__global__ __launch_bounds__(256) void k1_embed_norm(
    const int* __restrict__ ends, const float* __restrict__ emb,
    unsigned short* __restrict__ xh, unsigned short* __restrict__ xl) {
  int wave = threadIdx.x >> 6, lane = threadIdx.x & 63;
  int vec = blockIdx.x * 4 + wave;            // vec = s*B + b (ends is [S][B])
  int b = vec & (B_N - 1), s = vec >> 7;
  int v = ends[vec];
  const float* row = emb + (size_t)v * D_EMB;
  float e0 = row[lane], e1 = row[lane + 64], e2 = row[lane + 128], e3 = row[lane + 192];
  float e4 = (lane + 256 < D_EMB) ? row[lane + 256] : 0.f;
  float ss = e0*e0 + e1*e1 + e2*e2 + e3*e3 + e4*e4;
  #pragma unroll
  for (int m = 1; m < 64; m <<= 1) ss += __shfl_xor(ss, m);
  float sc = 1.0f / fmaxf(sqrtf(ss), 1e-8f);
  size_t base = ((size_t)b * S_LEN + s) * KP;
  float xs[5] = { e0*sc, e1*sc, e2*sc, e3*sc, (lane + 256 < D_EMB) ? e4*sc : 0.f };
  #pragma unroll
  for (int i = 0; i < 5; ++i) {
    unsigned short hi = f32_to_bf16(xs[i]);
    unsigned short lo = f32_to_bf16(xs[i] - bf16_to_f32(hi));
    xh[base + lane + 64*i] = hi;
    xl[base + lane + 64*i] = lo;
  }
}

// ---------------------------------------------------------------------------
// K2: feats[i][b] = max_{j<i} dot(xn[i,b], xn[j,b]); feats[0]=0
// Split-bf16 MFMA 32x32x16 (hi*hi + hi*lo + lo*hi).
// R19: (a) double-buffered B staging — flattened (jc,kc) tile stream,
// stage tile n+1 into buf[(n+1)&1] while computing tile n: 1 barrier/tile
// (was 2) and staging latency overlaps MFMA. Same data + same MFMA order
// -> bit-identical feats. (b) heavy-first dispatch: ic = 7 - blockIdx.y
// so the (ic+1)-proportional heavy blocks launch first, not in the tail.
// ---------------------------------------------------------------------------
#define KC  80
#define LDP 88      // LDS row stride in ushorts (conflict-friendly, 16B aligned)

__global__ __launch_bounds__(256) void k2_feats(
    const unsigned short* __restrict__ xh, const unsigned short* __restrict__ xl,
    float* __restrict__ feats) {
  __shared__ __align__(16) unsigned short sBh[2][64*LDP], sBl[2][64*LDP];
  __shared__ float rbuf[4][32];
  int b   = blockIdx.x;          // 0..127 (b&7 selects XCD)
  int ic  = 7 - blockIdx.y;      // heavy-first
  int tid = threadIdx.x;
  int wave = tid >> 6, lane = tid & 63;
  int itl = wave & 1, jtl = wave >> 1;
  int itg = ic * 2 + itl;        // global 32-row i-tile index
  size_t xbase = (size_t)b * S_LEN * KP;
  int arow0 = ic * 64;
  // my A row (m = lane&31) and k-quad offset
  const size_t arowoff = xbase + (size_t)(arow0 + itl * 32 + (lane & 31)) * KP
                       + (size_t)((lane >> 5) * 8);

  float rm[16];
  #pragma unroll
  for (int r = 0; r < 16; ++r) rm[r] = -INFINITY;

  const int NT = (ic + 1) * 4;   // tiles: n = jc*4 + kc

  // prologue: stage tile 0 into buf 0
  for (int u = tid; u < 640; u += 256) {
    int r = u / 10, sg = u % 10;
    size_t gb = xbase + (size_t)r * KP + sg * 8;
    int la = r * LDP + sg * 8;
    *(ushort8*)&sBh[0][la] = *(const ushort8*)&xh[gb];
    *(ushort8*)&sBl[0][la] = *(const ushort8*)&xl[gb];
  }
  __syncthreads();

  float16v acc;
  for (int n = 0; n < NT; ++n) {
    int jc = n >> 2, kc = n & 3, buf = n & 1;
    if (kc == 0) {
      #pragma unroll
      for (int r = 0; r < 16; ++r) acc[r] = 0.f;
    }
    // prefetch next tile into the other buffer (overlaps this tile's MFMA)
    if (n + 1 < NT) {
      int jn = (n + 1) >> 2, kn = (n + 1) & 3;
      for (int u = tid; u < 640; u += 256) {
        int r = u / 10, sg = u % 10;
        size_t gb = xbase + (size_t)(jn * 64 + r) * KP + kn * KC + sg * 8;
        int la = r * LDP + sg * 8;
        *(ushort8*)&sBh[buf ^ 1][la] = *(const ushort8*)&xh[gb];
        *(ushort8*)&sBl[buf ^ 1][la] = *(const ushort8*)&xl[gb];
      }
    }
    int jt = jc * 2 + jtl;
    bool active = (jt <= itg);
    if (active) {
      // A fragments: direct global->register (10 x 16B per lane, L2-hot)
      short8 a_h[5], a_l[5];
      #pragma unroll
      for (int ks = 0; ks < 5; ++ks) {
        size_t ga = arowoff + kc * KC + ks * 16;
        a_h[ks] = *(const short8*)&xh[ga];
        a_l[ks] = *(const short8*)&xl[ga];
      }
      int br = (jtl * 32 + (lane & 31)) * LDP;
      int kq = (lane >> 5) * 8;
      #pragma unroll
      for (int ks = 0; ks < 5; ++ks) {
        short8 b_h = *(const short8*)&sBh[buf][br + ks*16 + kq];
        short8 b_l = *(const short8*)&sBl[buf][br + ks*16 + kq];
        acc = __builtin_amdgcn_mfma_f32_32x32x16_bf16(a_h[ks], b_h, acc, 0, 0, 0);
        acc = __builtin_amdgcn_mfma_f32_32x32x16_bf16(a_h[ks], b_l, acc, 0, 0, 0);
        acc = __builtin_amdgcn_mfma_f32_32x32x16_bf16(a_l[ks], b_h, acc, 0, 0, 0);
      }
    }
    __syncthreads();   // next buffer staged AND this buffer free for n+2
    if (kc == 3 && active) {
      int colg = jt * 32 + (lane & 31);
      #pragma unroll
      for (int r = 0; r < 16; ++r) {
        int rowg = itg * 32 + (r & 3) + 8*(r >> 2) + 4*(lane >> 5);
        float v = acc[r];
        if (jt == itg && colg >= rowg) v = -INFINITY;  // causal: j<i
        rm[r] = fmaxf(rm[r], v);
      }
    }
  }
  #pragma unroll
  for (int r = 0; r < 16; ++r) {
    float v = rm[r];
    v = fmaxf(v, __shfl_xor(v, 1));
    v = fmaxf(v, __shfl_xor(v, 2));
    v = fmaxf(v, __shfl_xor(v, 4));
    v = fmaxf(v, __shfl_xor(v, 8));
    v = fmaxf(v, __shfl_xor(v, 16));
    rm[r] = v;
  }
  if ((lane & 31) == 0) {
    int half = lane >> 5;
    #pragma unroll
    for (int r = 0; r < 16; ++r)
      rbuf[wave][(r & 3) + 8*(r >> 2) + 4*half] = rm[r];
  }
  __syncthreads();
  if (tid < 64) {   // merge jt-parities, write feats
    int it2 = tid >> 5, rl = tid & 31;
    float v = fmaxf(rbuf[it2][rl], rbuf[it2 + 2][rl]);
    int i = ic * 64 + it2 * 32 + rl;
    feats[i * B_N + b] = (i == 0) ? 0.0f : v;
  }
}

// ---------------------------------------------------------------------------
// K3: GRU, persistent cooperative kernel. 256 WGs x 512 thr (R17 — FROZEN).
// FROZEN R8 signal skeleton: wg-scope producer stores -> vmcnt(0) ->
// __syncthreads -> tid0 WG-flag store; consumer flag poll with s_sleep.
// LEDGER: per-wave PRODUCER flag fanouts fast-fail 3/3 (R5/R6/R9);
// counter-RMW flags regress (R10); poison-spin data-as-signal +16% (R12);
// R13 coalesced consumer load -360us; R14 fragment-major layout -253us;
// R15 conflict-free reduce -19us (conflicts overlapped); R16 chain split
// +24us (1-wave/SIMD is ISSUE-limited, not dep-stall); R17 2 waves/SIMD
// -46us; R18 16WGx32j REGRESSED +233us (halving WGs doubled per-WG serial
// work; parallelism loss > protocol gain) -> 32 WGs x 16 j is the sweet
// spot; k3 is near its protocol floor (~2 L2 RTT signal + 1 RTT drain).
// ---------------------------------------------------------------------------
#define HW64 (B_N * H_N / 2)   // 8B words per parity buffer (= 32768)

__global__ __launch_bounds__(512, 1) void k3_gru(
    const float* __restrict__ feats,
    const float* __restrict__ w_ih, const float* __restrict__ w_hh,
    const float* __restrict__ b_ih, const float* __restrict__ b_hh,
    const float* __restrict__ fc_w, const float* __restrict__ fc_b,
    unsigned long long* __restrict__ hq, unsigned int* __restrict__ bars,
    float* __restrict__ out) {
  __shared__ __align__(16) float4v red2[8][16][16];   // [wave][batch][j] = {r,z,n,pad}
  __shared__ float osum[256];
  int tid = threadIdx.x;
  int wave = tid >> 6, lane = tid & 63;
  int g = blockIdx.x & 7, s = blockIdx.x >> 3;

  // --- stationary W_hh fragments in registers (B-operand: n=lane&15, k=quad*8+j)
  // wave w covers global K slice [64w, 64w+64): ks in {0,1} local.
  short8 wfh[3][2], wfl[3][2];
  {
    int nloc = lane & 15;
    int kq = (lane >> 4) * 8;
    #pragma unroll
    for (int gt = 0; gt < 3; ++gt) {
      const float* wr = w_hh + (size_t)(gt * H_N + s * 16 + nloc) * H_N;
      #pragma unroll
      for (int ks = 0; ks < 2; ++ks) {
        int k0 = wave * 64 + ks * 32 + kq;
        short8 h8, l8;
        #pragma unroll
        for (int j = 0; j < 8; ++j) {
          float wv = wr[k0 + j];
          unsigned short hi = f32_to_bf16(wv);
          unsigned short lo = f32_to_bf16(wv - bf16_to_f32(hi));
          h8[j] = (short)hi; l8[j] = (short)lo;
        }
        wfh[gt][ks] = h8; wfl[gt][ks] = l8;
      }
    }
  }
  // --- per-thread gate constants: gate thread = (bb, jj), tid<256 only
  const bool gater = (tid < 256);
  int bb = tid >> 4, jj = tid & 15;           // bb valid as batch only if gater
  int jr = s * 16 + jj;
  float wihr = w_ih[jr], wihz = w_ih[H_N + jr], wihn = w_ih[2*H_N + jr];
  float bir = b_ih[jr],  biz = b_ih[H_N + jr],  bin_ = b_ih[2*H_N + jr];
  float bhr = b_hh[jr],  bhz = b_hh[H_N + jr],  bhn = b_hh[2*H_N + jr];
  float fcw = fc_w[jr];
  int gb = g * 16 + (bb & 15);
  float h_old = 0.f;
  // R17: wave w polls only its 4 producers s in [4w, 4w+4)
  const unsigned int* fp = bars + g * 32 + wave * 4 + (lane & 3);
  unsigned int* myflag = bars + g * 32 + s;

  // producer indexing (unchanged): j = s*16+jj
  //   fragment C = g*16 + (s>>3)*4 + ((s>>1)&3); q = (2s + (jj>>3))&3
  const int Cp = g * 16 + (s >> 3) * 4 + ((s >> 1) & 3);
  const int qp = (2 * s + (jj >> 3)) & 3;
  const size_t prodoff = (size_t)Cp * 512 + (size_t)qp * 128 + (size_t)(bb & 15) * 8;
  // consumer base: wave w owns fragments 2w, 2w+1
  const size_t cbase = (size_t)(g * 16 + wave * 2) * 512 + (size_t)lane * 8;

  for (int t = 0; t < S_LEN; ++t) {
    // feats load hoisted above the poll — independent, overlaps the spin
    float x = gater ? feats[t * B_N + gb] : 0.f;
    float sr = 0.f, sz = 0.f, sn = 0.f;
    if (t > 0) {
      // ---- wait: this wave's 4 producers stored h_{t-1} (flag >= t)
      {
        const unsigned tgt = (unsigned)t;
        for (;;) {
          unsigned f = __hip_atomic_load(fp, __ATOMIC_RELAXED, __HIP_MEMORY_SCOPE_AGENT);
          if (__ballot(f < tgt) == 0ull) break;
          __builtin_amdgcn_s_sleep(1);
        }
        asm volatile("" ::: "memory");
      }
      const unsigned short* hh =
          (const unsigned short*)(hq + (size_t)((t - 1) & 1) * HW64);
      const unsigned short* hbase = hh + cbase;        // hi fragments
      const unsigned short* lbase = hbase + 65536;     // lo fragments
      // 4x dwordx4 sc1 (L1-bypass), each 64-lane instr = 1KB contiguous.
      uint4v rh0, rh1, rl0, rl1;
      asm volatile(
        "global_load_dwordx4 %0, %4, off sc1\n\t"
        "global_load_dwordx4 %1, %4, off offset:1024 sc1\n\t"
        "global_load_dwordx4 %2, %5, off sc1\n\t"
        "global_load_dwordx4 %3, %5, off offset:1024 sc1\n\t"
        "s_waitcnt vmcnt(0)"
        : "=&v"(rh0), "=&v"(rh1), "=&v"(rl0), "=&v"(rl1)
        : "v"(hbase), "v"(lbase)
        : "memory");
      short8 ah0 = as_short8(rh0), ah1 = as_short8(rh1);
      short8 al0 = as_short8(rl0), al1 = as_short8(rl1);
      float4v a0, a1, a2;
      #pragma unroll
      for (int r = 0; r < 4; ++r) { a0[r] = 0.f; a1[r] = 0.f; a2[r] = 0.f; }
      // 18 MFMAs: 2 local ks x {hh, hl, lh} x 3 gates (same per-ks order as R15)
      a0 = __builtin_amdgcn_mfma_f32_16x16x32_bf16(ah0, wfh[0][0], a0, 0,0,0);
      a1 = __builtin_amdgcn_mfma_f32_16x16x32_bf16(ah0, wfh[1][0], a1, 0,0,0);
      a2 = __builtin_amdgcn_mfma_f32_16x16x32_bf16(ah0, wfh[2][0], a2, 0,0,0);
      a0 = __builtin_amdgcn_mfma_f32_16x16x32_bf16(ah0, wfl[0][0], a0, 0,0,0);
      a1 = __builtin_amdgcn_mfma_f32_16x16x32_bf16(ah0, wfl[1][0], a1, 0,0,0);
      a2 = __builtin_amdgcn_mfma_f32_16x16x32_bf16(ah0, wfl[2][0], a2, 0,0,0);
      a0 = __builtin_amdgcn_mfma_f32_16x16x32_bf16(al0, wfh[0][0], a0, 0,0,0);
      a1 = __builtin_amdgcn_mfma_f32_16x16x32_bf16(al0, wfh[1][0], a1, 0,0,0);
      a2 = __builtin_amdgcn_mfma_f32_16x16x32_bf16(al0, wfh[2][0], a2, 0,0,0);
      a0 = __builtin_amdgcn_mfma_f32_16x16x32_bf16(ah1, wfh[0][1], a0, 0,0,0);
      a1 = __builtin_amdgcn_mfma_f32_16x16x32_bf16(ah1, wfh[1][1], a1, 0,0,0);
      a2 = __builtin_amdgcn_mfma_f32_16x16x32_bf16(ah1, wfh[2][1], a2, 0,0,0);
      a0 = __builtin_amdgcn_mfma_f32_16x16x32_bf16(ah1, wfl[0][1], a0, 0,0,0);
      a1 = __builtin_amdgcn_mfma_f32_16x16x32_bf16(ah1, wfl[1][1], a1, 0,0,0);
      a2 = __builtin_amdgcn_mfma_f32_16x16x32_bf16(ah1, wfl[2][1], a2, 0,0,0);
      a0 = __builtin_amdgcn_mfma_f32_16x16x32_bf16(al1, wfh[0][1], a0, 0,0,0);
      a1 = __builtin_amdgcn_mfma_f32_16x16x32_bf16(al1, wfh[1][1], a1, 0,0,0);
      a2 = __builtin_amdgcn_mfma_f32_16x16x32_bf16(al1, wfh[2][1], a2, 0,0,0);
      // C/D: row(batch)=(lane>>4)*4+reg, col(j)=lane&15. float4 {r,z,n,pad}.
      int colw = lane & 15, roww = (lane >> 4) * 4;
      #pragma unroll
      for (int r = 0; r < 4; ++r) {
        float4v w; w[0] = a0[r]; w[1] = a1[r]; w[2] = a2[r]; w[3] = 0.f;
        red2[wave][roww + r][colw] = w;
      }
      __syncthreads();
      if (gater) {
        float4v sv = red2[0][bb][jj];
        #pragma unroll
        for (int w8 = 1; w8 < 8; ++w8) sv += red2[w8][bb][jj];
        sr = sv[0]; sz = sv[1]; sn = sv[2];
      }
    }
    if (gater) {
      // gates: exact identities on fast exp; clamp to dodge inf/inf
      float ar_ = fminf(fmaxf(x * wihr + bir + sr + bhr, -30.f), 30.f);
      float az_ = fminf(fmaxf(x * wihz + biz + sz + bhz, -30.f), 30.f);
      float r_ = __builtin_amdgcn_rcpf(1.f + __expf(-ar_));
      float z_ = __builtin_amdgcn_rcpf(1.f + __expf(-az_));
      float an_ = fminf(fmaxf(x * wihn + bin_ + r_ * (sn + bhn), -30.f), 30.f);
      float en = __expf(-2.f * an_);
      float n_ = (1.f - en) * __builtin_amdgcn_rcpf(1.f + en);
      float h_new = (1.f - z_) * n_ + z_ * h_old;
      h_old = h_new;
      if (t < S_LEN - 1) {
        unsigned short hi16 = f32_to_bf16(h_new);
        unsigned short lo16 = f32_to_bf16(h_new - bf16_to_f32(hi16));
        // 3-round shfl_xor allgather -> full 8-elem run in 4 dwords.
        unsigned myh = hi16, myl = lo16;
        unsigned oh = (unsigned)__shfl_xor((int)myh, 1);
        unsigned ol = (unsigned)__shfl_xor((int)myl, 1);
        bool od1 = (jj & 1) != 0;
        unsigned pH = od1 ? (oh | (myh << 16)) : (myh | (oh << 16));  // [e even|e odd]
        unsigned pL = od1 ? (ol | (myl << 16)) : (myl | (ol << 16));
        unsigned qh = (unsigned)__shfl_xor((int)pH, 2);
        unsigned ql = (unsigned)__shfl_xor((int)pL, 2);
        bool od2 = (jj & 2) != 0;
        unsigned h01 = od2 ? qh : pH, h23 = od2 ? pH : qh;   // pairs e01,e23
        unsigned l01 = od2 ? ql : pL, l23 = od2 ? pL : ql;
        unsigned xh01 = (unsigned)__shfl_xor((int)h01, 4);
        unsigned xh23 = (unsigned)__shfl_xor((int)h23, 4);
        unsigned xl01 = (unsigned)__shfl_xor((int)l01, 4);
        unsigned xl23 = (unsigned)__shfl_xor((int)l23, 4);
        bool od4 = (jj & 4) != 0;
        uint4v runH, runL;
        runH[0] = od4 ? xh01 : h01; runH[1] = od4 ? xh23 : h23;
        runH[2] = od4 ? h01 : xh01; runH[3] = od4 ? h23 : xh23;
        runL[0] = od4 ? xl01 : l01; runL[1] = od4 ? xl23 : l23;
        runL[2] = od4 ? l01 : xl01; runL[3] = od4 ? l23 : xl23;
        unsigned short* hh = (unsigned short*)(hq + (size_t)(t & 1) * HW64);
        if ((jj & 3) == 0) {   // jj=0,8: hi run; jj=4,12: lo run
          if ((jj & 4) == 0) *(uint4v*)(hh + prodoff)         = runH;
          else               *(uint4v*)(hh + 65536 + prodoff) = runL;
        }
      }
    }
    if (t < S_LEN - 1) {
      // drain own stores (ack at L2), WG barrier, then flag (wg-scope)
      asm volatile("s_waitcnt vmcnt(0)" ::: "memory");
      __syncthreads();
      if (tid == 0)
        __hip_atomic_store(myflag, (unsigned)(t + 1),
                           __ATOMIC_RELAXED, __HIP_MEMORY_SCOPE_WORKGROUP);
    }
  }
  // --- epilogue: out[b] = h_last . fc_w + fc_b
  if (gater) osum[tid] = h_old * fcw;
  __syncthreads();
  if (gater && jj == 0) {
    float acc = 0.f;
    #pragma unroll
    for (int q = 0; q < 16; ++q) acc += osum[bb * 16 + q];
    if (s == 0) acc += fc_b[0];
    atomicAdd(&out[gb], acc);
  }
}

// ---------------------------------------------------------------------------
extern "C" void kernel_launch(void* const* d_in, const int* in_sizes, int n_in,
                              void* d_out, int out_size, void* d_ws, size_t ws_size,
                              hipStream_t stream) {
  (void)in_sizes; (void)n_in; (void)out_size; (void)ws_size;
  const int*   ends = (const int*)d_in[1];
  const float* emb  = (const float*)d_in[3];
  const float* w_ih = (const float*)d_in[4];
  const float* w_hh = (const float*)d_in[5];
  const float* b_ih = (const float*)d_in[6];
  const float* b_hh = (const float*)d_in[7];
  const float* fc_w = (const float*)d_in[8];
  const float* fc_b = (const float*)d_in[9];
  float* out = (float*)d_out;

  size_t xn_elems = (size_t)B_N * S_LEN * KP;
  unsigned short* xh = (unsigned short*)d_ws;
  unsigned short* xl = xh + xn_elems;
  float* feats = (float*)(xl + xn_elems);
  unsigned long long* hq = (unsigned long long*)(feats + S_LEN * B_N);
  unsigned int* bars = (unsigned int*)(hq + 2 * (size_t)HW64);

  hipMemsetAsync(out, 0, sizeof(float) * B_N, stream);
  hipMemsetAsync(bars, 0, 4096, stream);   // 8 groups x 32 WG flags

  k1_embed_norm<<<dim3(S_LEN * B_N / 4), dim3(256), 0, stream>>>(ends, emb, xh, xl);
  k2_feats<<<dim3(B_N, 8), dim3(256), 0, stream>>>(xh, xl, feats);

  void* args[] = { (void*)&feats, (void*)&w_ih, (void*)&w_hh, (void*)&b_ih,
                   (void*)&b_hh, (void*)&fc_w, (void*)&fc_b,
                   (void*)&hq, (void*)&bars, (void*)&out };
  hipLaunchCooperativeKernel((void*)k3_gru, dim3(256), dim3(512), args, 0, stream);
}

// Round 9
// 1032.017 us; speedup vs baseline: 1.2727x; 1.0366x over previous
//
#include <hip/hip_runtime.h>
#include <hip/hip_bf16.h>
#include <math.h>

// Problem: S=512, B=128, V=50257, D=300, H=512
#define S_LEN 512
#define B_N   128
#define D_EMB 300
#define KP    320   // D padded to multiple of 32 (zero-filled)
#define H_N   512

typedef __attribute__((ext_vector_type(8)))  short short8;       // 8 bf16 (4 VGPRs)
typedef __attribute__((ext_vector_type(8)))  unsigned short ushort8;
typedef __attribute__((ext_vector_type(4)))  unsigned int uint4v;
typedef __attribute__((ext_vector_type(4)))  float float4v;
typedef __attribute__((ext_vector_type(16))) float float16v;

__device__ __forceinline__ unsigned short f32_to_bf16(float f) {
  unsigned u = __float_as_uint(f);
  u = (u + 0x7fffu + ((u >> 16) & 1u)) >> 16;   // RNE
  return (unsigned short)u;
}
__device__ __forceinline__ float bf16_to_f32(unsigned short h) {
  return __uint_as_float(((unsigned)h) << 16);
}
__device__ __forceinline__ short8 as_short8(uint4v v) {
  union { uint4v u; short8 s; } c; c.u = v; return c.s;
}

// ---------------------------------------------------------------------------
// K1: embeds = embed_mat[ends]; xn = embeds / max(||embeds||,eps)
// writes xn as split bf16 (hi+lo), layout [b][s][KP], k 300..319 zero.
// ---------------------------------------------------------------------------
__global__ __launch_bounds__(256) void k1_embed_norm(
    const int* __restrict__ ends, const float* __restrict__ emb,
    unsigned short* __restrict__ xh, unsigned short* __restrict__ xl) {
  int wave = threadIdx.x >> 6, lane = threadIdx.x & 63;
  int vec = blockIdx.x * 4 + wave;            // vec = s*B + b (ends is [S][B])
  int b = vec & (B_N - 1), s = vec >> 7;
  int v = ends[vec];
  const float* row = emb + (size_t)v * D_EMB;
  float e0 = row[lane], e1 = row[lane + 64], e2 = row[lane + 128], e3 = row[lane + 192];
  float e4 = (lane + 256 < D_EMB) ? row[lane + 256] : 0.f;
  float ss = e0*e0 + e1*e1 + e2*e2 + e3*e3 + e4*e4;
  #pragma unroll
  for (int m = 1; m < 64; m <<= 1) ss += __shfl_xor(ss, m);
  float sc = 1.0f / fmaxf(sqrtf(ss), 1e-8f);
  size_t base = ((size_t)b * S_LEN + s) * KP;
  float xs[5] = { e0*sc, e1*sc, e2*sc, e3*sc, (lane + 256 < D_EMB) ? e4*sc : 0.f };
  #pragma unroll
  for (int i = 0; i < 5; ++i) {
    unsigned short hi = f32_to_bf16(xs[i]);
    unsigned short lo = f32_to_bf16(xs[i] - bf16_to_f32(hi));
    xh[base + lane + 64*i] = hi;
    xl[base + lane + 64*i] = lo;
  }
}

// ---------------------------------------------------------------------------
// K2: feats[i][b] = max_{j<i} dot(xn[i,b], xn[j,b]); feats[0]=0
// Split-bf16 MFMA 32x32x16 (hi*hi + hi*lo + lo*hi).
// R19: dbuf B staging (1 barrier/tile), heavy-first (ic = 7-blockIdx.y).
// R20: A fragments for ALL 4 kc hoisted to registers ONCE per block
// (a_h/a_l[4][5] = 160 VGPR). Previously A was re-loaded from global per
// (jc,kc): (ic+1)x4 x 40KB = 5.76MB/b of L3-served traffic; now 160KB/b.
// k2 is L3-BW bound (xh/xl = 84MB >> 32MB L2), so -39% total traffic.
// Loop structure jc-outer / kc-inner-UNROLLED so a[kc][ks] indices are
// compile-time (rule #20: runtime-indexed reg arrays spill to scratch).
// Same (jc,kc,ks) MFMA order -> bit-identical feats.
// ---------------------------------------------------------------------------
#define KC  80
#define LDP 88      // LDS row stride in ushorts (conflict-friendly, 16B aligned)

__global__ __launch_bounds__(256) void k2_feats(
    const unsigned short* __restrict__ xh, const unsigned short* __restrict__ xl,
    float* __restrict__ feats) {
  __shared__ __align__(16) unsigned short sBh[2][64*LDP], sBl[2][64*LDP];
  __shared__ float rbuf[4][32];
  int b   = blockIdx.x;          // 0..127 (b&7 selects XCD)
  int ic  = 7 - blockIdx.y;      // heavy-first
  int tid = threadIdx.x;
  int wave = tid >> 6, lane = tid & 63;
  int itl = wave & 1, jtl = wave >> 1;
  int itg = ic * 2 + itl;        // global 32-row i-tile index
  size_t xbase = (size_t)b * S_LEN * KP;
  int arow0 = ic * 64;
  // my A row (m = lane&31) and k-quad offset
  const size_t arowoff = xbase + (size_t)(arow0 + itl * 32 + (lane & 31)) * KP
                       + (size_t)((lane >> 5) * 8);

  // R20: A fragments, all 4 kc, loaded once (registers for the whole block)
  short8 a_h[4][5], a_l[4][5];
  #pragma unroll
  for (int kc = 0; kc < 4; ++kc) {
    #pragma unroll
    for (int ks = 0; ks < 5; ++ks) {
      size_t ga = arowoff + kc * KC + ks * 16;
      a_h[kc][ks] = *(const short8*)&xh[ga];
      a_l[kc][ks] = *(const short8*)&xl[ga];
    }
  }

  float rm[16];
  #pragma unroll
  for (int r = 0; r < 16; ++r) rm[r] = -INFINITY;

  // prologue: stage tile (jc=0, kc=0) into buf 0
  for (int u = tid; u < 640; u += 256) {
    int r = u / 10, sg = u % 10;
    size_t gb = xbase + (size_t)r * KP + sg * 8;
    int la = r * LDP + sg * 8;
    *(ushort8*)&sBh[0][la] = *(const ushort8*)&xh[gb];
    *(ushort8*)&sBl[0][la] = *(const ushort8*)&xl[gb];
  }
  __syncthreads();

  int buf = 0;
  for (int jc = 0; jc <= ic; ++jc) {
    int jt = jc * 2 + jtl;
    bool active = (jt <= itg);
    float16v acc;
    #pragma unroll
    for (int r = 0; r < 16; ++r) acc[r] = 0.f;

    #pragma unroll
    for (int kc = 0; kc < 4; ++kc) {
      // prefetch next tile of the (jc-major, kc-minor) stream into buf^1
      bool last = (jc == ic) && (kc == 3);
      if (!last) {
        int jn = (kc < 3) ? jc : jc + 1;
        int kn = (kc + 1) & 3;
        for (int u = tid; u < 640; u += 256) {
          int r = u / 10, sg = u % 10;
          size_t gb = xbase + (size_t)(jn * 64 + r) * KP + kn * KC + sg * 8;
          int la = r * LDP + sg * 8;
          *(ushort8*)&sBh[buf ^ 1][la] = *(const ushort8*)&xh[gb];
          *(ushort8*)&sBl[buf ^ 1][la] = *(const ushort8*)&xl[gb];
        }
      }
      if (active) {
        int br = (jtl * 32 + (lane & 31)) * LDP;
        int kq = (lane >> 5) * 8;
        #pragma unroll
        for (int ks = 0; ks < 5; ++ks) {
          short8 b_h = *(const short8*)&sBh[buf][br + ks*16 + kq];
          short8 b_l = *(const short8*)&sBl[buf][br + ks*16 + kq];
          acc = __builtin_amdgcn_mfma_f32_32x32x16_bf16(a_h[kc][ks], b_h, acc, 0, 0, 0);
          acc = __builtin_amdgcn_mfma_f32_32x32x16_bf16(a_h[kc][ks], b_l, acc, 0, 0, 0);
          acc = __builtin_amdgcn_mfma_f32_32x32x16_bf16(a_l[kc][ks], b_h, acc, 0, 0, 0);
        }
      }
      __syncthreads();   // staged buf^1 ready AND buf free for re-stage
      buf ^= 1;
    }
    if (active) {
      int colg = jt * 32 + (lane & 31);
      #pragma unroll
      for (int r = 0; r < 16; ++r) {
        int rowg = itg * 32 + (r & 3) + 8*(r >> 2) + 4*(lane >> 5);
        float v = acc[r];
        if (jt == itg && colg >= rowg) v = -INFINITY;  // causal: j<i
        rm[r] = fmaxf(rm[r], v);
      }
    }
  }
  #pragma unroll
  for (int r = 0; r < 16; ++r) {
    float v = rm[r];
    v = fmaxf(v, __shfl_xor(v, 1));
    v = fmaxf(v, __shfl_xor(v, 2));
    v = fmaxf(v, __shfl_xor(v, 4));
    v = fmaxf(v, __shfl_xor(v, 8));
    v = fmaxf(v, __shfl_xor(v, 16));
    rm[r] = v;
  }
  if ((lane & 31) == 0) {
    int half = lane >> 5;
    #pragma unroll
    for (int r = 0; r < 16; ++r)
      rbuf[wave][(r & 3) + 8*(r >> 2) + 4*half] = rm[r];
  }
  __syncthreads();
  if (tid < 64) {   // merge jt-parities, write feats
    int it2 = tid >> 5, rl = tid & 31;
    float v = fmaxf(rbuf[it2][rl], rbuf[it2 + 2][rl]);
    int i = ic * 64 + it2 * 32 + rl;
    feats[i * B_N + b] = (i == 0) ? 0.0f : v;
  }
}

// ---------------------------------------------------------------------------
// K3: GRU, persistent cooperative kernel. 256 WGs x 512 thr (R17 — FROZEN).
// FROZEN R8 signal skeleton: wg-scope producer stores -> vmcnt(0) ->
// __syncthreads -> tid0 WG-flag store; consumer flag poll (R20: no s_sleep
// — poll is 1 dword/wave/RTT ~5B/cy/XCD, 3 orders below R12's failure
// mode; shaves ~60cy discovery latency per step).
// LEDGER: per-wave PRODUCER flag fanouts fast-fail 3/3 (R5/R6/R9);
// counter-RMW flags regress (R10); poison-spin data-as-signal +16% (R12);
// R13 coalesced consumer load -360us; R14 fragment-major layout -253us;
// R15 conflict-free reduce -19us (conflicts overlapped); R16 chain split
// +24us (1-wave/SIMD is ISSUE-limited, not dep-stall); R17 2 waves/SIMD
// -46us; R18 16WGx32j +233us (parallelism loss > protocol gain) -> 32
// WGs x 16 j sweet spot; k3 near protocol floor (~2 L2 RTT + drain).
// ---------------------------------------------------------------------------
#define HW64 (B_N * H_N / 2)   // 8B words per parity buffer (= 32768)

__global__ __launch_bounds__(512, 1) void k3_gru(
    const float* __restrict__ feats,
    const float* __restrict__ w_ih, const float* __restrict__ w_hh,
    const float* __restrict__ b_ih, const float* __restrict__ b_hh,
    const float* __restrict__ fc_w, const float* __restrict__ fc_b,
    unsigned long long* __restrict__ hq, unsigned int* __restrict__ bars,
    float* __restrict__ out) {
  __shared__ __align__(16) float4v red2[8][16][16];   // [wave][batch][j] = {r,z,n,pad}
  __shared__ float osum[256];
  int tid = threadIdx.x;
  int wave = tid >> 6, lane = tid & 63;
  int g = blockIdx.x & 7, s = blockIdx.x >> 3;

  // --- stationary W_hh fragments in registers (B-operand: n=lane&15, k=quad*8+j)
  // wave w covers global K slice [64w, 64w+64): ks in {0,1} local.
  short8 wfh[3][2], wfl[3][2];
  {
    int nloc = lane & 15;
    int kq = (lane >> 4) * 8;
    #pragma unroll
    for (int gt = 0; gt < 3; ++gt) {
      const float* wr = w_hh + (size_t)(gt * H_N + s * 16 + nloc) * H_N;
      #pragma unroll
      for (int ks = 0; ks < 2; ++ks) {
        int k0 = wave * 64 + ks * 32 + kq;
        short8 h8, l8;
        #pragma unroll
        for (int j = 0; j < 8; ++j) {
          float wv = wr[k0 + j];
          unsigned short hi = f32_to_bf16(wv);
          unsigned short lo = f32_to_bf16(wv - bf16_to_f32(hi));
          h8[j] = (short)hi; l8[j] = (short)lo;
        }
        wfh[gt][ks] = h8; wfl[gt][ks] = l8;
      }
    }
  }
  // --- per-thread gate constants: gate thread = (bb, jj), tid<256 only
  const bool gater = (tid < 256);
  int bb = tid >> 4, jj = tid & 15;           // bb valid as batch only if gater
  int jr = s * 16 + jj;
  float wihr = w_ih[jr], wihz = w_ih[H_N + jr], wihn = w_ih[2*H_N + jr];
  float bir = b_ih[jr],  biz = b_ih[H_N + jr],  bin_ = b_ih[2*H_N + jr];
  float bhr = b_hh[jr],  bhz = b_hh[H_N + jr],  bhn = b_hh[2*H_N + jr];
  float fcw = fc_w[jr];
  int gb = g * 16 + (bb & 15);
  float h_old = 0.f;
  // R17: wave w polls only its 4 producers s in [4w, 4w+4)
  const unsigned int* fp = bars + g * 32 + wave * 4 + (lane & 3);
  unsigned int* myflag = bars + g * 32 + s;

  // producer indexing (unchanged): j = s*16+jj
  //   fragment C = g*16 + (s>>3)*4 + ((s>>1)&3); q = (2s + (jj>>3))&3
  const int Cp = g * 16 + (s >> 3) * 4 + ((s >> 1) & 3);
  const int qp = (2 * s + (jj >> 3)) & 3;
  const size_t prodoff = (size_t)Cp * 512 + (size_t)qp * 128 + (size_t)(bb & 15) * 8;
  // consumer base: wave w owns fragments 2w, 2w+1
  const size_t cbase = (size_t)(g * 16 + wave * 2) * 512 + (size_t)lane * 8;

  for (int t = 0; t < S_LEN; ++t) {
    // feats load hoisted above the poll — independent, overlaps the spin
    float x = gater ? feats[t * B_N + gb] : 0.f;
    float sr = 0.f, sz = 0.f, sn = 0.f;
    if (t > 0) {
      // ---- wait: this wave's 4 producers stored h_{t-1} (flag >= t)
      {
        const unsigned tgt = (unsigned)t;
        for (;;) {
          unsigned f = __hip_atomic_load(fp, __ATOMIC_RELAXED, __HIP_MEMORY_SCOPE_AGENT);
          if (__ballot(f < tgt) == 0ull) break;
        }
        asm volatile("" ::: "memory");
      }
      const unsigned short* hh =
          (const unsigned short*)(hq + (size_t)((t - 1) & 1) * HW64);
      const unsigned short* hbase = hh + cbase;        // hi fragments
      const unsigned short* lbase = hbase + 65536;     // lo fragments
      // 4x dwordx4 sc1 (L1-bypass), each 64-lane instr = 1KB contiguous.
      uint4v rh0, rh1, rl0, rl1;
      asm volatile(
        "global_load_dwordx4 %0, %4, off sc1\n\t"
        "global_load_dwordx4 %1, %4, off offset:1024 sc1\n\t"
        "global_load_dwordx4 %2, %5, off sc1\n\t"
        "global_load_dwordx4 %3, %5, off offset:1024 sc1\n\t"
        "s_waitcnt vmcnt(0)"
        : "=&v"(rh0), "=&v"(rh1), "=&v"(rl0), "=&v"(rl1)
        : "v"(hbase), "v"(lbase)
        : "memory");
      short8 ah0 = as_short8(rh0), ah1 = as_short8(rh1);
      short8 al0 = as_short8(rl0), al1 = as_short8(rl1);
      float4v a0, a1, a2;
      #pragma unroll
      for (int r = 0; r < 4; ++r) { a0[r] = 0.f; a1[r] = 0.f; a2[r] = 0.f; }
      // 18 MFMAs: 2 local ks x {hh, hl, lh} x 3 gates (same per-ks order as R15)
      a0 = __builtin_amdgcn_mfma_f32_16x16x32_bf16(ah0, wfh[0][0], a0, 0,0,0);
      a1 = __builtin_amdgcn_mfma_f32_16x16x32_bf16(ah0, wfh[1][0], a1, 0,0,0);
      a2 = __builtin_amdgcn_mfma_f32_16x16x32_bf16(ah0, wfh[2][0], a2, 0,0,0);
      a0 = __builtin_amdgcn_mfma_f32_16x16x32_bf16(ah0, wfl[0][0], a0, 0,0,0);
      a1 = __builtin_amdgcn_mfma_f32_16x16x32_bf16(ah0, wfl[1][0], a1, 0,0,0);
      a2 = __builtin_amdgcn_mfma_f32_16x16x32_bf16(ah0, wfl[2][0], a2, 0,0,0);
      a0 = __builtin_amdgcn_mfma_f32_16x16x32_bf16(al0, wfh[0][0], a0, 0,0,0);
      a1 = __builtin_amdgcn_mfma_f32_16x16x32_bf16(al0, wfh[1][0], a1, 0,0,0);
      a2 = __builtin_amdgcn_mfma_f32_16x16x32_bf16(al0, wfh[2][0], a2, 0,0,0);
      a0 = __builtin_amdgcn_mfma_f32_16x16x32_bf16(ah1, wfh[0][1], a0, 0,0,0);
      a1 = __builtin_amdgcn_mfma_f32_16x16x32_bf16(ah1, wfh[1][1], a1, 0,0,0);
      a2 = __builtin_amdgcn_mfma_f32_16x16x32_bf16(ah1, wfh[2][1], a2, 0,0,0);
      a0 = __builtin_amdgcn_mfma_f32_16x16x32_bf16(ah1, wfl[0][1], a0, 0,0,0);
      a1 = __builtin_amdgcn_mfma_f32_16x16x32_bf16(ah1, wfl[1][1], a1, 0,0,0);
      a2 = __builtin_amdgcn_mfma_f32_16x16x32_bf16(ah1, wfl[2][1], a2, 0,0,0);
      a0 = __builtin_amdgcn_mfma_f32_16x16x32_bf16(al1, wfh[0][1], a0, 0,0,0);
      a1 = __builtin_amdgcn_mfma_f32_16x16x32_bf16(al1, wfh[1][1], a1, 0,0,0);
      a2 = __builtin_amdgcn_mfma_f32_16x16x32_bf16(al1, wfh[2][1], a2, 0,0,0);
      // C/D: row(batch)=(lane>>4)*4+reg, col(j)=lane&15. float4 {r,z,n,pad}.
      int colw = lane & 15, roww = (lane >> 4) * 4;
      #pragma unroll
      for (int r = 0; r < 4; ++r) {
        float4v w; w[0] = a0[r]; w[1] = a1[r]; w[2] = a2[r]; w[3] = 0.f;
        red2[wave][roww + r][colw] = w;
      }
      __syncthreads();
      if (gater) {
        float4v sv = red2[0][bb][jj];
        #pragma unroll
        for (int w8 = 1; w8 < 8; ++w8) sv += red2[w8][bb][jj];
        sr = sv[0]; sz = sv[1]; sn = sv[2];
      }
    }
    if (gater) {
      // gates: exact identities on fast exp; clamp to dodge inf/inf
      float ar_ = fminf(fmaxf(x * wihr + bir + sr + bhr, -30.f), 30.f);
      float az_ = fminf(fmaxf(x * wihz + biz + sz + bhz, -30.f), 30.f);
      float r_ = __builtin_amdgcn_rcpf(1.f + __expf(-ar_));
      float z_ = __builtin_amdgcn_rcpf(1.f + __expf(-az_));
      float an_ = fminf(fmaxf(x * wihn + bin_ + r_ * (sn + bhn), -30.f), 30.f);
      float en = __expf(-2.f * an_);
      float n_ = (1.f - en) * __builtin_amdgcn_rcpf(1.f + en);
      float h_new = (1.f - z_) * n_ + z_ * h_old;
      h_old = h_new;
      if (t < S_LEN - 1) {
        unsigned short hi16 = f32_to_bf16(h_new);
        unsigned short lo16 = f32_to_bf16(h_new - bf16_to_f32(hi16));
        // 3-round shfl_xor allgather -> full 8-elem run in 4 dwords.
        unsigned myh = hi16, myl = lo16;
        unsigned oh = (unsigned)__shfl_xor((int)myh, 1);
        unsigned ol = (unsigned)__shfl_xor((int)myl, 1);
        bool od1 = (jj & 1) != 0;
        unsigned pH = od1 ? (oh | (myh << 16)) : (myh | (oh << 16));  // [e even|e odd]
        unsigned pL = od1 ? (ol | (myl << 16)) : (myl | (ol << 16));
        unsigned qh = (unsigned)__shfl_xor((int)pH, 2);
        unsigned ql = (unsigned)__shfl_xor((int)pL, 2);
        bool od2 = (jj & 2) != 0;
        unsigned h01 = od2 ? qh : pH, h23 = od2 ? pH : qh;   // pairs e01,e23
        unsigned l01 = od2 ? ql : pL, l23 = od2 ? pL : ql;
        unsigned xh01 = (unsigned)__shfl_xor((int)h01, 4);
        unsigned xh23 = (unsigned)__shfl_xor((int)h23, 4);
        unsigned xl01 = (unsigned)__shfl_xor((int)l01, 4);
        unsigned xl23 = (unsigned)__shfl_xor((int)l23, 4);
        bool od4 = (jj & 4) != 0;
        uint4v runH, runL;
        runH[0] = od4 ? xh01 : h01; runH[1] = od4 ? xh23 : h23;
        runH[2] = od4 ? h01 : xh01; runH[3] = od4 ? h23 : xh23;
        runL[0] = od4 ? xl01 : l01; runL[1] = od4 ? xl23 : l23;
        runL[2] = od4 ? l01 : xl01; runL[3] = od4 ? l23 : xl23;
        unsigned short* hh = (unsigned short*)(hq + (size_t)(t & 1) * HW64);
        if ((jj & 3) == 0) {   // jj=0,8: hi run; jj=4,12: lo run
          if ((jj & 4) == 0) *(uint4v*)(hh + prodoff)         = runH;
          else               *(uint4v*)(hh + 65536 + prodoff) = runL;
        }
      }
    }
    if (t < S_LEN - 1) {
      // drain own stores (ack at L2), WG barrier, then flag (wg-scope)
      asm volatile("s_waitcnt vmcnt(0)" ::: "memory");
      __syncthreads();
      if (tid == 0)
        __hip_atomic_store(myflag, (unsigned)(t + 1),
                           __ATOMIC_RELAXED, __HIP_MEMORY_SCOPE_WORKGROUP);
    }
  }
  // --- epilogue: out[b] = h_last . fc_w + fc_b
  if (gater) osum[tid] = h_old * fcw;
  __syncthreads();
  if (gater && jj == 0) {
    float acc = 0.f;
    #pragma unroll
    for (int q = 0; q < 16; ++q) acc += osum[bb * 16 + q];
    if (s == 0) acc += fc_b[0];
    atomicAdd(&out[gb], acc);
  }
}

// ---------------------------------------------------------------------------
extern "C" void kernel_launch(void* const* d_in, const int* in_sizes, int n_in,
                              void* d_out, int out_size, void* d_ws, size_t ws_size,
                              hipStream_t stream) {
  (void)in_sizes; (void)n_in; (void)out_size; (void)ws_size;
  const int*   ends = (const int*)d_in[1];
  const float* emb  = (const float*)d_in[3];
  const float* w_ih = (const float*)d_in[4];
  const float* w_hh = (const float*)d_in[5];
  const float* b_ih = (const float*)d_in[6];
  const float* b_hh = (const float*)d_in[7];
  const float* fc_w = (const float*)d_in[8];
  const float* fc_b = (const float*)d_in[9];
  float* out = (float*)d_out;

  size_t xn_elems = (size_t)B_N * S_LEN * KP;
  unsigned short* xh = (unsigned short*)d_ws;
  unsigned short* xl = xh + xn_elems;
  float* feats = (float*)(xl + xn_elems);
  unsigned long long* hq = (unsigned long long*)(feats + S_LEN * B_N);
  unsigned int* bars = (unsigned int*)(hq + 2 * (size_t)HW64);

  hipMemsetAsync(out, 0, sizeof(float) * B_N, stream);
  hipMemsetAsync(bars, 0, 4096, stream);   // 8 groups x 32 WG flags

  k1_embed_norm<<<dim3(S_LEN * B_N / 4), dim3(256), 0, stream>>>(ends, emb, xh, xl);
  k2_feats<<<dim3(B_N, 8), dim3(256), 0, stream>>>(xh, xl, feats);

  void* args[] = { (void*)&feats, (void*)&w_ih, (void*)&w_hh, (void*)&b_ih,
                   (void*)&b_hh, (void*)&fc_w, (void*)&fc_b,
                   (void*)&hq, (void*)&bars, (void*)&out };
  hipLaunchCooperativeKernel((void*)k3_gru, dim3(256), dim3(512), args, 0, stream);
}

// Round 10
// 1026.237 us; speedup vs baseline: 1.2799x; 1.0056x over previous
//
#include <hip/hip_runtime.h>
#include <hip/hip_bf16.h>
#include <math.h>

// Problem: S=512, B=128, V=50257, D=300, H=512
#define S_LEN 512
#define B_N   128
#define D_EMB 300
#define KP    320   // D padded to multiple of 32 (zero-filled)
#define H_N   512

typedef __attribute__((ext_vector_type(8)))  short short8;       // 8 bf16 (4 VGPRs)
typedef __attribute__((ext_vector_type(8)))  unsigned short ushort8;
typedef __attribute__((ext_vector_type(4)))  unsigned int uint4v;
typedef __attribute__((ext_vector_type(4)))  float float4v;
typedef __attribute__((ext_vector_type(16))) float float16v;

__device__ __forceinline__ unsigned short f32_to_bf16(float f) {
  unsigned u = __float_as_uint(f);
  u = (u + 0x7fffu + ((u >> 16) & 1u)) >> 16;   // RNE
  return (unsigned short)u;
}
__device__ __forceinline__ float bf16_to_f32(unsigned short h) {
  return __uint_as_float(((unsigned)h) << 16);
}
__device__ __forceinline__ short8 as_short8(uint4v v) {
  union { uint4v u; short8 s; } c; c.u = v; return c.s;
}

// ---------------------------------------------------------------------------
// K1: embeds = embed_mat[ends]; xn = embeds / max(||embeds||,eps)
// writes xn as split bf16 (hi+lo), layout [b][s][KP], k 300..319 zero.
// ---------------------------------------------------------------------------
__global__ __launch_bounds__(256) void k1_embed_norm(
    const int* __restrict__ ends, const float* __restrict__ emb,
    unsigned short* __restrict__ xh, unsigned short* __restrict__ xl) {
  int wave = threadIdx.x >> 6, lane = threadIdx.x & 63;
  int vec = blockIdx.x * 4 + wave;            // vec = s*B + b (ends is [S][B])
  int b = vec & (B_N - 1), s = vec >> 7;
  int v = ends[vec];
  const float* row = emb + (size_t)v * D_EMB;
  float e0 = row[lane], e1 = row[lane + 64], e2 = row[lane + 128], e3 = row[lane + 192];
  float e4 = (lane + 256 < D_EMB) ? row[lane + 256] : 0.f;
  float ss = e0*e0 + e1*e1 + e2*e2 + e3*e3 + e4*e4;
  #pragma unroll
  for (int m = 1; m < 64; m <<= 1) ss += __shfl_xor(ss, m);
  float sc = 1.0f / fmaxf(sqrtf(ss), 1e-8f);
  size_t base = ((size_t)b * S_LEN + s) * KP;
  float xs[5] = { e0*sc, e1*sc, e2*sc, e3*sc, (lane + 256 < D_EMB) ? e4*sc : 0.f };
  #pragma unroll
  for (int i = 0; i < 5; ++i) {
    unsigned short hi = f32_to_bf16(xs[i]);
    unsigned short lo = f32_to_bf16(xs[i] - bf16_to_f32(hi));
    xh[base + lane + 64*i] = hi;
    xl[base + lane + 64*i] = lo;
  }
}

// ---------------------------------------------------------------------------
// K2: feats[i][b] = max_{j<i} dot(xn[i,b], xn[j,b]); feats[0]=0
// Split-bf16 MFMA 32x32x16 (hi*hi + hi*lo + lo*hi).
// R20: A fragments (all 4 kc) hoisted to registers once per block; k2 is
// L3-BW bound (confirmed: -70us, matched the traffic model).
// R21: 128-ROW BLOCKS (grid 128 x 4, ic2 = 3-blockIdx.y heavy-first).
// Each wave owns ONE 32-row i-tile (itg = ic2*4+wave); staged 64-row
// j-tiles are shared by all 4 waves -> each j-tile staged ceil((jt+1)/4)
// times instead of (8-jt) times: 144 -> 80 staged tiles per b (-44%
// staging traffic). Two accumulators per wave (jtl 0/1) max into the
// wave-private rm; no cross-wave jt-parity merge in the epilogue.
// Same (kc,ks) MFMA order per (i,j) pair -> identical dot values; max is
// order-independent -> identical feats.
// ---------------------------------------------------------------------------
#define KC  80
#define LDP 88      // LDS row stride in ushorts (conflict-friendly, 16B aligned)

__global__ __launch_bounds__(256) void k2_feats(
    const unsigned short* __restrict__ xh, const unsigned short* __restrict__ xl,
    float* __restrict__ feats) {
  __shared__ __align__(16) unsigned short sBh[2][64*LDP], sBl[2][64*LDP];
  int b   = blockIdx.x;          // 0..127 (b&7 selects XCD)
  int ic2 = 3 - blockIdx.y;      // heavy-first; rows [ic2*128, ic2*128+128)
  int tid = threadIdx.x;
  int wave = tid >> 6, lane = tid & 63;
  int itg = ic2 * 4 + wave;      // this wave's global 32-row i-tile
  size_t xbase = (size_t)b * S_LEN * KP;
  // my A row (m = lane&31) and k-quad offset
  const size_t arowoff = xbase + (size_t)(itg * 32 + (lane & 31)) * KP
                       + (size_t)((lane >> 5) * 8);

  // A fragments, all 4 kc, loaded once (registers for the whole block)
  short8 a_h[4][5], a_l[4][5];
  #pragma unroll
  for (int kc = 0; kc < 4; ++kc) {
    #pragma unroll
    for (int ks = 0; ks < 5; ++ks) {
      size_t ga = arowoff + kc * KC + ks * 16;
      a_h[kc][ks] = *(const short8*)&xh[ga];
      a_l[kc][ks] = *(const short8*)&xl[ga];
    }
  }

  float rm[16];
  #pragma unroll
  for (int r = 0; r < 16; ++r) rm[r] = -INFINITY;

  const int NJ = 2 * ic2 + 2;    // 64-row j-tiles needed by this block

  // prologue: stage tile (jc=0, kc=0) into buf 0
  for (int u = tid; u < 640; u += 256) {
    int r = u / 10, sg = u % 10;
    size_t gb = xbase + (size_t)r * KP + sg * 8;
    int la = r * LDP + sg * 8;
    *(ushort8*)&sBh[0][la] = *(const ushort8*)&xh[gb];
    *(ushort8*)&sBl[0][la] = *(const ushort8*)&xl[gb];
  }
  __syncthreads();

  int buf = 0;
  for (int jc = 0; jc < NJ; ++jc) {
    int jt0 = jc * 2, jt1 = jc * 2 + 1;
    bool act0 = (jt0 <= itg), act1 = (jt1 <= itg);
    float16v acc0, acc1;
    #pragma unroll
    for (int r = 0; r < 16; ++r) { acc0[r] = 0.f; acc1[r] = 0.f; }

    #pragma unroll
    for (int kc = 0; kc < 4; ++kc) {
      // prefetch next tile of the (jc-major, kc-minor) stream into buf^1
      bool last = (jc == NJ - 1) && (kc == 3);
      if (!last) {
        int jn = (kc < 3) ? jc : jc + 1;
        int kn = (kc + 1) & 3;
        for (int u = tid; u < 640; u += 256) {
          int r = u / 10, sg = u % 10;
          size_t gb = xbase + (size_t)(jn * 64 + r) * KP + kn * KC + sg * 8;
          int la = r * LDP + sg * 8;
          *(ushort8*)&sBh[buf ^ 1][la] = *(const ushort8*)&xh[gb];
          *(ushort8*)&sBl[buf ^ 1][la] = *(const ushort8*)&xl[gb];
        }
      }
      int kq = (lane >> 5) * 8;
      if (act0) {
        int br = (lane & 31) * LDP;          // j rows 0..31 of tile
        #pragma unroll
        for (int ks = 0; ks < 5; ++ks) {
          short8 b_h = *(const short8*)&sBh[buf][br + ks*16 + kq];
          short8 b_l = *(const short8*)&sBl[buf][br + ks*16 + kq];
          acc0 = __builtin_amdgcn_mfma_f32_32x32x16_bf16(a_h[kc][ks], b_h, acc0, 0, 0, 0);
          acc0 = __builtin_amdgcn_mfma_f32_32x32x16_bf16(a_h[kc][ks], b_l, acc0, 0, 0, 0);
          acc0 = __builtin_amdgcn_mfma_f32_32x32x16_bf16(a_l[kc][ks], b_h, acc0, 0, 0, 0);
        }
      }
      if (act1) {
        int br = (32 + (lane & 31)) * LDP;   // j rows 32..63 of tile
        #pragma unroll
        for (int ks = 0; ks < 5; ++ks) {
          short8 b_h = *(const short8*)&sBh[buf][br + ks*16 + kq];
          short8 b_l = *(const short8*)&sBl[buf][br + ks*16 + kq];
          acc1 = __builtin_amdgcn_mfma_f32_32x32x16_bf16(a_h[kc][ks], b_h, acc1, 0, 0, 0);
          acc1 = __builtin_amdgcn_mfma_f32_32x32x16_bf16(a_h[kc][ks], b_l, acc1, 0, 0, 0);
          acc1 = __builtin_amdgcn_mfma_f32_32x32x16_bf16(a_l[kc][ks], b_h, acc1, 0, 0, 0);
        }
      }
      __syncthreads();   // staged buf^1 ready AND buf free for re-stage
      buf ^= 1;
    }
    // causal mask + max into wave-private rm
    if (act0) {
      int colg = jt0 * 32 + (lane & 31);
      #pragma unroll
      for (int r = 0; r < 16; ++r) {
        int rowg = itg * 32 + (r & 3) + 8*(r >> 2) + 4*(lane >> 5);
        float v = acc0[r];
        if (jt0 == itg && colg >= rowg) v = -INFINITY;  // causal: j<i
        rm[r] = fmaxf(rm[r], v);
      }
    }
    if (act1) {
      int colg = jt1 * 32 + (lane & 31);
      #pragma unroll
      for (int r = 0; r < 16; ++r) {
        int rowg = itg * 32 + (r & 3) + 8*(r >> 2) + 4*(lane >> 5);
        float v = acc1[r];
        if (jt1 == itg && colg >= rowg) v = -INFINITY;
        rm[r] = fmaxf(rm[r], v);
      }
    }
  }
  // reduce over the 32 columns within each half, write feats directly
  #pragma unroll
  for (int r = 0; r < 16; ++r) {
    float v = rm[r];
    v = fmaxf(v, __shfl_xor(v, 1));
    v = fmaxf(v, __shfl_xor(v, 2));
    v = fmaxf(v, __shfl_xor(v, 4));
    v = fmaxf(v, __shfl_xor(v, 8));
    v = fmaxf(v, __shfl_xor(v, 16));
    rm[r] = v;
  }
  if ((lane & 31) == 0) {
    int half = lane >> 5;
    #pragma unroll
    for (int r = 0; r < 16; ++r) {
      int i = itg * 32 + (r & 3) + 8*(r >> 2) + 4*half;
      feats[i * B_N + b] = (i == 0) ? 0.0f : rm[r];
    }
  }
}

// ---------------------------------------------------------------------------
// K3: GRU, persistent cooperative kernel. 256 WGs x 512 thr (R17 — FROZEN).
// FROZEN R8 signal skeleton: wg-scope producer stores -> vmcnt(0) ->
// __syncthreads -> tid0 WG-flag store; consumer flag poll WITH s_sleep(1).
// LEDGER: per-wave PRODUCER flag fanouts fast-fail 3/3 (R5/R6/R9);
// counter-RMW flags regress (R10); poison-spin data-as-signal +16% (R12);
// R13 coalesced consumer load -360us; R14 fragment-major layout -253us;
// R15 conflict-free reduce -19us (conflicts overlapped); R16 chain split
// +24us (1-wave/SIMD is ISSUE-limited, not dep-stall); R17 2 waves/SIMD
// -46us; R18 16WGx32j +233us (parallelism loss > protocol gain); R20
// s_sleep removal REGRESSED +33us (unpaced poll hammers L2, slows
// producer acks — R12 mechanism at lower magnitude) -> s_sleep(1) FROZEN.
// k3 near protocol floor (~2 L2 RTT + drain + skew over 32 producers).
// ---------------------------------------------------------------------------
#define HW64 (B_N * H_N / 2)   // 8B words per parity buffer (= 32768)

__global__ __launch_bounds__(512, 1) void k3_gru(
    const float* __restrict__ feats,
    const float* __restrict__ w_ih, const float* __restrict__ w_hh,
    const float* __restrict__ b_ih, const float* __restrict__ b_hh,
    const float* __restrict__ fc_w, const float* __restrict__ fc_b,
    unsigned long long* __restrict__ hq, unsigned int* __restrict__ bars,
    float* __restrict__ out) {
  __shared__ __align__(16) float4v red2[8][16][16];   // [wave][batch][j] = {r,z,n,pad}
  __shared__ float osum[256];
  int tid = threadIdx.x;
  int wave = tid >> 6, lane = tid & 63;
  int g = blockIdx.x & 7, s = blockIdx.x >> 3;

  // --- stationary W_hh fragments in registers (B-operand: n=lane&15, k=quad*8+j)
  // wave w covers global K slice [64w, 64w+64): ks in {0,1} local.
  short8 wfh[3][2], wfl[3][2];
  {
    int nloc = lane & 15;
    int kq = (lane >> 4) * 8;
    #pragma unroll
    for (int gt = 0; gt < 3; ++gt) {
      const float* wr = w_hh + (size_t)(gt * H_N + s * 16 + nloc) * H_N;
      #pragma unroll
      for (int ks = 0; ks < 2; ++ks) {
        int k0 = wave * 64 + ks * 32 + kq;
        short8 h8, l8;
        #pragma unroll
        for (int j = 0; j < 8; ++j) {
          float wv = wr[k0 + j];
          unsigned short hi = f32_to_bf16(wv);
          unsigned short lo = f32_to_bf16(wv - bf16_to_f32(hi));
          h8[j] = (short)hi; l8[j] = (short)lo;
        }
        wfh[gt][ks] = h8; wfl[gt][ks] = l8;
      }
    }
  }
  // --- per-thread gate constants: gate thread = (bb, jj), tid<256 only
  const bool gater = (tid < 256);
  int bb = tid >> 4, jj = tid & 15;           // bb valid as batch only if gater
  int jr = s * 16 + jj;
  float wihr = w_ih[jr], wihz = w_ih[H_N + jr], wihn = w_ih[2*H_N + jr];
  float bir = b_ih[jr],  biz = b_ih[H_N + jr],  bin_ = b_ih[2*H_N + jr];
  float bhr = b_hh[jr],  bhz = b_hh[H_N + jr],  bhn = b_hh[2*H_N + jr];
  float fcw = fc_w[jr];
  int gb = g * 16 + (bb & 15);
  float h_old = 0.f;
  // R17: wave w polls only its 4 producers s in [4w, 4w+4)
  const unsigned int* fp = bars + g * 32 + wave * 4 + (lane & 3);
  unsigned int* myflag = bars + g * 32 + s;

  // producer indexing (unchanged): j = s*16+jj
  //   fragment C = g*16 + (s>>3)*4 + ((s>>1)&3); q = (2s + (jj>>3))&3
  const int Cp = g * 16 + (s >> 3) * 4 + ((s >> 1) & 3);
  const int qp = (2 * s + (jj >> 3)) & 3;
  const size_t prodoff = (size_t)Cp * 512 + (size_t)qp * 128 + (size_t)(bb & 15) * 8;
  // consumer base: wave w owns fragments 2w, 2w+1
  const size_t cbase = (size_t)(g * 16 + wave * 2) * 512 + (size_t)lane * 8;

  for (int t = 0; t < S_LEN; ++t) {
    // feats load hoisted above the poll — independent, overlaps the spin
    float x = gater ? feats[t * B_N + gb] : 0.f;
    float sr = 0.f, sz = 0.f, sn = 0.f;
    if (t > 0) {
      // ---- wait: this wave's 4 producers stored h_{t-1} (flag >= t)
      {
        const unsigned tgt = (unsigned)t;
        for (;;) {
          unsigned f = __hip_atomic_load(fp, __ATOMIC_RELAXED, __HIP_MEMORY_SCOPE_AGENT);
          if (__ballot(f < tgt) == 0ull) break;
          __builtin_amdgcn_s_sleep(1);
        }
        asm volatile("" ::: "memory");
      }
      const unsigned short* hh =
          (const unsigned short*)(hq + (size_t)((t - 1) & 1) * HW64);
      const unsigned short* hbase = hh + cbase;        // hi fragments
      const unsigned short* lbase = hbase + 65536;     // lo fragments
      // 4x dwordx4 sc1 (L1-bypass), each 64-lane instr = 1KB contiguous.
      uint4v rh0, rh1, rl0, rl1;
      asm volatile(
        "global_load_dwordx4 %0, %4, off sc1\n\t"
        "global_load_dwordx4 %1, %4, off offset:1024 sc1\n\t"
        "global_load_dwordx4 %2, %5, off sc1\n\t"
        "global_load_dwordx4 %3, %5, off offset:1024 sc1\n\t"
        "s_waitcnt vmcnt(0)"
        : "=&v"(rh0), "=&v"(rh1), "=&v"(rl0), "=&v"(rl1)
        : "v"(hbase), "v"(lbase)
        : "memory");
      short8 ah0 = as_short8(rh0), ah1 = as_short8(rh1);
      short8 al0 = as_short8(rl0), al1 = as_short8(rl1);
      float4v a0, a1, a2;
      #pragma unroll
      for (int r = 0; r < 4; ++r) { a0[r] = 0.f; a1[r] = 0.f; a2[r] = 0.f; }
      // 18 MFMAs: 2 local ks x {hh, hl, lh} x 3 gates (same per-ks order as R15)
      a0 = __builtin_amdgcn_mfma_f32_16x16x32_bf16(ah0, wfh[0][0], a0, 0,0,0);
      a1 = __builtin_amdgcn_mfma_f32_16x16x32_bf16(ah0, wfh[1][0], a1, 0,0,0);
      a2 = __builtin_amdgcn_mfma_f32_16x16x32_bf16(ah0, wfh[2][0], a2, 0,0,0);
      a0 = __builtin_amdgcn_mfma_f32_16x16x32_bf16(ah0, wfl[0][0], a0, 0,0,0);
      a1 = __builtin_amdgcn_mfma_f32_16x16x32_bf16(ah0, wfl[1][0], a1, 0,0,0);
      a2 = __builtin_amdgcn_mfma_f32_16x16x32_bf16(ah0, wfl[2][0], a2, 0,0,0);
      a0 = __builtin_amdgcn_mfma_f32_16x16x32_bf16(al0, wfh[0][0], a0, 0,0,0);
      a1 = __builtin_amdgcn_mfma_f32_16x16x32_bf16(al0, wfh[1][0], a1, 0,0,0);
      a2 = __builtin_amdgcn_mfma_f32_16x16x32_bf16(al0, wfh[2][0], a2, 0,0,0);
      a0 = __builtin_amdgcn_mfma_f32_16x16x32_bf16(ah1, wfh[0][1], a0, 0,0,0);
      a1 = __builtin_amdgcn_mfma_f32_16x16x32_bf16(ah1, wfh[1][1], a1, 0,0,0);
      a2 = __builtin_amdgcn_mfma_f32_16x16x32_bf16(ah1, wfh[2][1], a2, 0,0,0);
      a0 = __builtin_amdgcn_mfma_f32_16x16x32_bf16(ah1, wfl[0][1], a0, 0,0,0);
      a1 = __builtin_amdgcn_mfma_f32_16x16x32_bf16(ah1, wfl[1][1], a1, 0,0,0);
      a2 = __builtin_amdgcn_mfma_f32_16x16x32_bf16(ah1, wfl[2][1], a2, 0,0,0);
      a0 = __builtin_amdgcn_mfma_f32_16x16x32_bf16(al1, wfh[0][1], a0, 0,0,0);
      a1 = __builtin_amdgcn_mfma_f32_16x16x32_bf16(al1, wfh[1][1], a1, 0,0,0);
      a2 = __builtin_amdgcn_mfma_f32_16x16x32_bf16(al1, wfh[2][1], a2, 0,0,0);
      // C/D: row(batch)=(lane>>4)*4+reg, col(j)=lane&15. float4 {r,z,n,pad}.
      int colw = lane & 15, roww = (lane >> 4) * 4;
      #pragma unroll
      for (int r = 0; r < 4; ++r) {
        float4v w; w[0] = a0[r]; w[1] = a1[r]; w[2] = a2[r]; w[3] = 0.f;
        red2[wave][roww + r][colw] = w;
      }
      __syncthreads();
      if (gater) {
        float4v sv = red2[0][bb][jj];
        #pragma unroll
        for (int w8 = 1; w8 < 8; ++w8) sv += red2[w8][bb][jj];
        sr = sv[0]; sz = sv[1]; sn = sv[2];
      }
    }
    if (gater) {
      // gates: exact identities on fast exp; clamp to dodge inf/inf
      float ar_ = fminf(fmaxf(x * wihr + bir + sr + bhr, -30.f), 30.f);
      float az_ = fminf(fmaxf(x * wihz + biz + sz + bhz, -30.f), 30.f);
      float r_ = __builtin_amdgcn_rcpf(1.f + __expf(-ar_));
      float z_ = __builtin_amdgcn_rcpf(1.f + __expf(-az_));
      float an_ = fminf(fmaxf(x * wihn + bin_ + r_ * (sn + bhn), -30.f), 30.f);
      float en = __expf(-2.f * an_);
      float n_ = (1.f - en) * __builtin_amdgcn_rcpf(1.f + en);
      float h_new = (1.f - z_) * n_ + z_ * h_old;
      h_old = h_new;
      if (t < S_LEN - 1) {
        unsigned short hi16 = f32_to_bf16(h_new);
        unsigned short lo16 = f32_to_bf16(h_new - bf16_to_f32(hi16));
        // 3-round shfl_xor allgather -> full 8-elem run in 4 dwords.
        unsigned myh = hi16, myl = lo16;
        unsigned oh = (unsigned)__shfl_xor((int)myh, 1);
        unsigned ol = (unsigned)__shfl_xor((int)myl, 1);
        bool od1 = (jj & 1) != 0;
        unsigned pH = od1 ? (oh | (myh << 16)) : (myh | (oh << 16));  // [e even|e odd]
        unsigned pL = od1 ? (ol | (myl << 16)) : (myl | (ol << 16));
        unsigned qh = (unsigned)__shfl_xor((int)pH, 2);
        unsigned ql = (unsigned)__shfl_xor((int)pL, 2);
        bool od2 = (jj & 2) != 0;
        unsigned h01 = od2 ? qh : pH, h23 = od2 ? pH : qh;   // pairs e01,e23
        unsigned l01 = od2 ? ql : pL, l23 = od2 ? pL : ql;
        unsigned xh01 = (unsigned)__shfl_xor((int)h01, 4);
        unsigned xh23 = (unsigned)__shfl_xor((int)h23, 4);
        unsigned xl01 = (unsigned)__shfl_xor((int)l01, 4);
        unsigned xl23 = (unsigned)__shfl_xor((int)l23, 4);
        bool od4 = (jj & 4) != 0;
        uint4v runH, runL;
        runH[0] = od4 ? xh01 : h01; runH[1] = od4 ? xh23 : h23;
        runH[2] = od4 ? h01 : xh01; runH[3] = od4 ? h23 : xh23;
        runL[0] = od4 ? xl01 : l01; runL[1] = od4 ? xl23 : l23;
        runL[2] = od4 ? l01 : xl01; runL[3] = od4 ? l23 : xl23;
        unsigned short* hh = (unsigned short*)(hq + (size_t)(t & 1) * HW64);
        if ((jj & 3) == 0) {   // jj=0,8: hi run; jj=4,12: lo run
          if ((jj & 4) == 0) *(uint4v*)(hh + prodoff)         = runH;
          else               *(uint4v*)(hh + 65536 + prodoff) = runL;
        }
      }
    }
    if (t < S_LEN - 1) {
      // drain own stores (ack at L2), WG barrier, then flag (wg-scope)
      asm volatile("s_waitcnt vmcnt(0)" ::: "memory");
      __syncthreads();
      if (tid == 0)
        __hip_atomic_store(myflag, (unsigned)(t + 1),
                           __ATOMIC_RELAXED, __HIP_MEMORY_SCOPE_WORKGROUP);
    }
  }
  // --- epilogue: out[b] = h_last . fc_w + fc_b
  if (gater) osum[tid] = h_old * fcw;
  __syncthreads();
  if (gater && jj == 0) {
    float acc = 0.f;
    #pragma unroll
    for (int q = 0; q < 16; ++q) acc += osum[bb * 16 + q];
    if (s == 0) acc += fc_b[0];
    atomicAdd(&out[gb], acc);
  }
}

// ---------------------------------------------------------------------------
extern "C" void kernel_launch(void* const* d_in, const int* in_sizes, int n_in,
                              void* d_out, int out_size, void* d_ws, size_t ws_size,
                              hipStream_t stream) {
  (void)in_sizes; (void)n_in; (void)out_size; (void)ws_size;
  const int*   ends = (const int*)d_in[1];
  const float* emb  = (const float*)d_in[3];
  const float* w_ih = (const float*)d_in[4];
  const float* w_hh = (const float*)d_in[5];
  const float* b_ih = (const float*)d_in[6];
  const float* b_hh = (const float*)d_in[7];
  const float* fc_w = (const float*)d_in[8];
  const float* fc_b = (const float*)d_in[9];
  float* out = (float*)d_out;

  size_t xn_elems = (size_t)B_N * S_LEN * KP;
  unsigned short* xh = (unsigned short*)d_ws;
  unsigned short* xl = xh + xn_elems;
  float* feats = (float*)(xl + xn_elems);
  unsigned long long* hq = (unsigned long long*)(feats + S_LEN * B_N);
  unsigned int* bars = (unsigned int*)(hq + 2 * (size_t)HW64);

  hipMemsetAsync(out, 0, sizeof(float) * B_N, stream);
  hipMemsetAsync(bars, 0, 4096, stream);   // 8 groups x 32 WG flags

  k1_embed_norm<<<dim3(S_LEN * B_N / 4), dim3(256), 0, stream>>>(ends, emb, xh, xl);
  k2_feats<<<dim3(B_N, 4), dim3(256), 0, stream>>>(xh, xl, feats);

  void* args[] = { (void*)&feats, (void*)&w_ih, (void*)&w_hh, (void*)&b_ih,
                   (void*)&b_hh, (void*)&fc_w, (void*)&fc_b,
                   (void*)&hq, (void*)&bars, (void*)&out };
  hipLaunchCooperativeKernel((void*)k3_gru, dim3(256), dim3(512), args, 0, stream);
}